// Round 1
// baseline (235.588 us; speedup 1.0000x reference)
//
#include <hip/hip_runtime.h>

// Fused MPNN layer for B=256, N=81, H=128, E=1620.
// Algebraic restructure:
//   P = X @ Wm1[:H],  Q = X @ Wm1[H:]            (node-level)
//   Hsum[t] = sum_{e: tgt=t} relu(P[src_e] + Q[t] + bm1)
//   agg[t]  = (Hsum[t] @ Wm2 + deg_t*bm2) / max(deg_t,1)
//   h2 = relu(X @ Wu1[:H] + agg @ Wu1[H:] + bu1)
//   x  = X + h2 @ Wu2 + bu2 ;  out = LayerNorm(x)*gamma + beta
// One workgroup per batch; everything lives in LDS (~149 KB).

#define BATCH 256
#define NN 81
#define HH 128
#define EE 1620
#define CHUNK 540   // EE / 3

__device__ __forceinline__ void gemm_acc(const float (*A)[HH], const float* __restrict__ Wg,
                                         int c, int row0, int nr, float (&acc)[41]) {
  // acc[i] += sum_k A[row0+i][k] * Wg[k*HH + c]
  float w[8];
#pragma unroll
  for (int j = 0; j < 8; ++j) w[j] = Wg[j * HH + c];
  for (int k0 = 0; k0 < HH; k0 += 8) {
    float wn[8];
    if (k0 + 8 < HH) {
#pragma unroll
      for (int j = 0; j < 8; ++j) wn[j] = Wg[(k0 + 8 + j) * HH + c];
    }
#pragma unroll
    for (int i = 0; i < 41; ++i) {
      if (i < nr) {
        const float4 a0 = *(const float4*)&A[row0 + i][k0];
        const float4 a1 = *(const float4*)&A[row0 + i][k0 + 4];
        acc[i] += a0.x * w[0] + a0.y * w[1] + a0.z * w[2] + a0.w * w[3]
                + a1.x * w[4] + a1.y * w[5] + a1.z * w[6] + a1.w * w[7];
      }
    }
#pragma unroll
    for (int j = 0; j < 8; ++j) w[j] = wn[j];
  }
}

__global__ __launch_bounds__(256, 1)
void mpnn_fused_kernel(const float* __restrict__ node,   // B*N*H
                       const int*   __restrict__ eidx,   // 2*E (row0=src, row1=tgt)
                       const float* __restrict__ Wm1,    // 2H*H
                       const float* __restrict__ bm1,
                       const float* __restrict__ Wm2,    // H*H
                       const float* __restrict__ bm2,
                       const float* __restrict__ Wu1,    // 2H*H
                       const float* __restrict__ bu1,
                       const float* __restrict__ Wu2,    // H*H
                       const float* __restrict__ bu2,
                       const float* __restrict__ gamma_,
                       const float* __restrict__ beta_,
                       float* __restrict__ out) {
  __shared__ float X[NN][HH];
  __shared__ float Pb[NN][HH];
  __shared__ float Qb[NN][HH];
  __shared__ int   edg[2 * EE];
  __shared__ int   csr[EE];
  __shared__ int   offs[NN + 1];
  __shared__ int   cnt3[3][NN];
  __shared__ int   base3[3][NN];
  __shared__ float biases[6][HH];  // bm1,bm2,bu1,bu2,gamma,beta

  const int tid  = threadIdx.x;
  const int lane = tid & 63;
  const int wave = tid >> 6;
  const int b    = blockIdx.x;

  // ---- stage X (float4), edge_index, biases ----
  {
    const float4* nf4 = (const float4*)(node + (size_t)b * NN * HH);
    float4* X4 = (float4*)&X[0][0];
    for (int i = tid; i < NN * HH / 4; i += 256) X4[i] = nf4[i];
    for (int i = tid; i < 2 * EE; i += 256) edg[i] = eidx[i];
    if (tid < HH) {
      biases[0][tid] = bm1[tid];
      biases[1][tid] = bm2[tid];
      biases[2][tid] = bu1[tid];
      biases[3][tid] = bu2[tid];
      biases[4][tid] = gamma_[tid];
      biases[5][tid] = beta_[tid];
    }
  }
  __syncthreads();

  // ---- deterministic CSR build (stable counting sort by target) ----
  if (tid < 3 * NN) {
    const int t = tid % NN, ch = tid / NN;
    const int e0 = ch * CHUNK, e1 = e0 + CHUNK;
    int cnt = 0;
    for (int e = e0; e < e1; ++e) cnt += (edg[EE + e] == t);
    cnt3[ch][t] = cnt;
  }
  __syncthreads();
  if (tid == 0) {
    int run = 0;
    for (int t = 0; t < NN; ++t) {
      offs[t] = run;
      base3[0][t] = run;
      base3[1][t] = base3[0][t] + cnt3[0][t];
      base3[2][t] = base3[1][t] + cnt3[1][t];
      run = base3[2][t] + cnt3[2][t];
    }
    offs[NN] = run;
  }
  __syncthreads();
  if (tid < 3 * NN) {
    const int t = tid % NN, ch = tid / NN;
    const int e0 = ch * CHUNK, e1 = e0 + CHUNK;
    int pos = base3[ch][t];
    for (int e = e0; e < e1; ++e)
      if (edg[EE + e] == t) csr[pos++] = edg[e];
  }
  __syncthreads();

  // ---- GEMM thread mapping: wave -> (col half, row half) ----
  const int c    = ((wave & 1) << 6) | lane;   // 0..127
  const int row0 = (wave >> 1) ? 41 : 0;
  const int nr   = (wave >> 1) ? 40 : 41;

  // ---- phase 2: P = X @ Wm1_top ; Q = X @ Wm1_bot ----
  {
    float acc[41];
#pragma unroll
    for (int i = 0; i < 41; ++i) acc[i] = 0.f;
    gemm_acc(X, Wm1, c, row0, nr, acc);
#pragma unroll
    for (int i = 0; i < 41; ++i) if (i < nr) Pb[row0 + i][c] = acc[i];
  }
  {
    float acc[41];
#pragma unroll
    for (int i = 0; i < 41; ++i) acc[i] = 0.f;
    gemm_acc(X, Wm1 + HH * HH, c, row0, nr, acc);
#pragma unroll
    for (int i = 0; i < 41; ++i) if (i < nr) Qb[row0 + i][c] = acc[i];
  }
  __syncthreads();

  // ---- phase 3: edge aggregation, Hsum[t] overwrites Qb[t] ----
  for (int t = wave; t < NN; t += 4) {
    const int o0 = offs[t], o1 = offs[t + 1];
    const float q0 = Qb[t][lane]      + biases[0][lane];
    const float q1 = Qb[t][lane + 64] + biases[0][lane + 64];
    float h0 = 0.f, h1 = 0.f;
    for (int e = o0; e < o1; ++e) {
      const int s = csr[e];
      h0 += fmaxf(Pb[s][lane]      + q0, 0.f);
      h1 += fmaxf(Pb[s][lane + 64] + q1, 0.f);
    }
    Qb[t][lane]      = h0;
    Qb[t][lane + 64] = h1;
  }
  __syncthreads();

  // ---- phase 4: agg = (Hsum @ Wm2 + deg*bm2)/max(deg,1) -> Pb ----
  {
    float acc[41];
#pragma unroll
    for (int i = 0; i < 41; ++i) acc[i] = 0.f;
    gemm_acc(Qb, Wm2, c, row0, nr, acc);
#pragma unroll
    for (int i = 0; i < 41; ++i) if (i < nr) {
      const int r = row0 + i;
      const float d = (float)(offs[r + 1] - offs[r]);
      const float inv = 1.f / fmaxf(d, 1.f);
      Pb[r][c] = (acc[i] + d * biases[1][c]) * inv;
    }
  }
  __syncthreads();

  // ---- phase 5: h2 = relu(X @ Wu1_top + agg @ Wu1_bot + bu1) -> Qb ----
  {
    float acc[41];
#pragma unroll
    for (int i = 0; i < 41; ++i) acc[i] = 0.f;
    gemm_acc(X,  Wu1,           c, row0, nr, acc);
    gemm_acc(Pb, Wu1 + HH * HH, c, row0, nr, acc);
#pragma unroll
    for (int i = 0; i < 41; ++i) if (i < nr)
      Qb[row0 + i][c] = fmaxf(acc[i] + biases[2][c], 0.f);
  }
  __syncthreads();

  // ---- phase 6: x = X + h2 @ Wu2 + bu2 (in place into X) ----
  {
    float acc[41];
#pragma unroll
    for (int i = 0; i < 41; ++i) acc[i] = 0.f;
    gemm_acc(Qb, Wu2, c, row0, nr, acc);
#pragma unroll
    for (int i = 0; i < 41; ++i) if (i < nr) {
      const int r = row0 + i;
      X[r][c] = X[r][c] + acc[i] + biases[3][c];
    }
  }
  __syncthreads();

  // ---- phase 7: LayerNorm per row + store ----
  for (int r = wave; r < NN; r += 4) {
    const float x0 = X[r][lane], x1 = X[r][lane + 64];
    float s = x0 + x1;
#pragma unroll
    for (int off = 32; off; off >>= 1) s += __shfl_xor(s, off);
    const float mu = s * (1.f / 128.f);
    const float d0 = x0 - mu, d1 = x1 - mu;
    float v = d0 * d0 + d1 * d1;
#pragma unroll
    for (int off = 32; off; off >>= 1) v += __shfl_xor(v, off);
    const float rstd = rsqrtf(v * (1.f / 128.f) + 1e-5f);
    const size_t o = ((size_t)b * NN + r) * HH;
    out[o + lane]      = d0 * rstd * biases[4][lane]      + biases[5][lane];
    out[o + lane + 64] = d1 * rstd * biases[4][lane + 64] + biases[5][lane + 64];
  }
}

extern "C" void kernel_launch(void* const* d_in, const int* in_sizes, int n_in,
                              void* d_out, int out_size, void* d_ws, size_t ws_size,
                              hipStream_t stream) {
  const float* node  = (const float*)d_in[0];
  const int*   eidx  = (const int*)  d_in[1];
  const float* Wm1   = (const float*)d_in[2];
  const float* bm1   = (const float*)d_in[3];
  const float* Wm2   = (const float*)d_in[4];
  const float* bm2   = (const float*)d_in[5];
  const float* Wu1   = (const float*)d_in[6];
  const float* bu1   = (const float*)d_in[7];
  const float* Wu2   = (const float*)d_in[8];
  const float* bu2   = (const float*)d_in[9];
  const float* gamma_= (const float*)d_in[10];
  const float* beta_ = (const float*)d_in[11];
  float* outp = (float*)d_out;

  hipLaunchKernelGGL(mpnn_fused_kernel, dim3(BATCH), dim3(256), 0, stream,
                     node, eidx, Wm1, bm1, Wm2, bm2, Wu1, bu1, Wu2, bu2,
                     gamma_, beta_, outp);
}

// Round 2
// 94.675 us; speedup vs baseline: 2.4884x; 2.4884x over previous
//
#include <hip/hip_runtime.h>

// Fused MPNN layer for B=256, N=81, H=128, E=1620 — MFMA bf16 version.
// Algebraic restructure (node-level GEMMs instead of edge-level):
//   P = X @ Wm1[:H],  Q = X @ Wm1[H:]
//   Hsum[t] = sum_{e: tgt=t} relu(P[src_e] + Q[t] + bm1)
//   agg[t]  = (Hsum[t] @ Wm2 + deg_t*bm2) / max(deg_t,1)
//   h2 = relu(X @ Wu1[:H] + agg @ Wu1[H:] + bu1)
//   x  = X + h2 @ Wu2 + bu2 ;  out = LayerNorm(x)*gamma + beta
// One workgroup (512 thr, 8 waves) per batch. GEMMs use mfma_f32_16x16x32_bf16.
// Weights pre-packed to bf16 MFMA-fragment order in d_ws by a tiny kernel.

#define NN 81
#define HH 128
#define EE 1620
#define CHUNK 540
#define MPAD 96   // 6 M-tiles of 16

typedef __attribute__((ext_vector_type(8))) short bf16x8;
typedef __attribute__((ext_vector_type(8))) unsigned short ushort8v;
typedef __attribute__((ext_vector_type(4))) unsigned short ushort4v;
typedef __attribute__((ext_vector_type(4))) float f32x4;

__device__ __forceinline__ unsigned short f2b(float f) {
  union { float f; unsigned u; } v; v.f = f;
  unsigned r = v.u + 0x7fffu + ((v.u >> 16) & 1u);
  return (unsigned short)(r >> 16);
}
__device__ __forceinline__ float b2f(unsigned short h) {
  union { unsigned u; float f; } v; v.u = ((unsigned)h) << 16;
  return v.f;
}

// ---------------- weight pack kernel: fp32 [K=128][N=128] -> bf16 frag order ----
// layout per matrix: [nt(8)][ks(4)][lane(64)][8 bf16]; 16384 ushorts per matrix.
// B-frag (16x16x32): lane l -> col = nt*16 + (l&15), k = ks*32 + (l>>4)*8 + j.
__global__ __launch_bounds__(256)
void pack_weights_kernel(const float* __restrict__ Wm1, const float* __restrict__ Wm2,
                         const float* __restrict__ Wu1, const float* __restrict__ Wu2,
                         unsigned short* __restrict__ wpk) {
  const int gid = blockIdx.x * 256 + threadIdx.x;
  if (gid >= 6 * 8 * 4 * 64) return;
  const int lane = gid & 63;
  const int t = gid >> 6;                 // mat*32 + nt*4 + ks
  const int ks = t & 3, nt = (t >> 2) & 7, mat = t >> 5;
  const float* src;
  if (mat == 0) src = Wm1;
  else if (mat == 1) src = Wm1 + HH * HH;
  else if (mat == 2) src = Wm2;
  else if (mat == 3) src = Wu1;
  else if (mat == 4) src = Wu1 + HH * HH;
  else src = Wu2;
  const int c = nt * 16 + (lane & 15);
  const int k0 = ks * 32 + (lane >> 4) * 8;
  bf16x8 pv;
#pragma unroll
  for (int j = 0; j < 8; ++j) pv[j] = (short)f2b(src[(k0 + j) * HH + c]);
  *(bf16x8*)(wpk + (size_t)mat * 16384 + (((nt * 4 + ks) * 64) + lane) * 8) = pv;
}

// ---------------- MFMA tile GEMM: 3 M-tiles x 2 N-tiles per wave, K=128 ----------
// Ab: swizzled bf16 LDS [96][128]  (byte ^= (row&7)<<4)
// Wp: packed global matrix (16384 ushorts)
__device__ __forceinline__ void gemm3x2(const unsigned short* Ab, const unsigned short* Wp,
                                        int lane, int mt0, int nt0, f32x4 acc[3][2]) {
  bf16x8 Bf[2][4];
#pragma unroll
  for (int nn = 0; nn < 2; ++nn)
#pragma unroll
    for (int ks = 0; ks < 4; ++ks)
      Bf[nn][ks] = *(const bf16x8*)(Wp + (((nt0 + nn) * 4 + ks) * 64 + lane) * 8);
  const int rl = lane & 15;
  const int kb = (lane >> 4) * 16;               // byte offset of this lane's k-chunk
  const unsigned swz = (unsigned)((rl & 7) << 4);
#pragma unroll
  for (int ks = 0; ks < 4; ++ks) {
#pragma unroll
    for (int mm = 0; mm < 3; ++mm) {
      const int r = (mt0 + mm) * 16 + rl;
      const unsigned byte = (unsigned)(r * 256) + (((unsigned)(ks * 64 + kb)) ^ swz);
      bf16x8 a = *(const bf16x8*)((const char*)Ab + byte);
#pragma unroll
      for (int nn = 0; nn < 2; ++nn)
        acc[mm][nn] = __builtin_amdgcn_mfma_f32_16x16x32_bf16(a, Bf[nn][ks], acc[mm][nn], 0, 0, 0);
    }
  }
}

__global__ __launch_bounds__(512)
void mpnn_mfma_kernel(const float* __restrict__ node, const int* __restrict__ eidx,
                      const float* __restrict__ bm1, const float* __restrict__ bm2,
                      const float* __restrict__ bu1, const float* __restrict__ bu2,
                      const float* __restrict__ gamma_, const float* __restrict__ beta_,
                      const unsigned short* __restrict__ wpk,
                      float* __restrict__ out) {
  __shared__ float X[NN][HH];                 // fp32 for residual + LN
  __shared__ unsigned short Xb[MPAD * HH];    // swizzled bf16 (rows 81..95 zero)
  __shared__ unsigned short bufP[MPAD * HH];  // P -> agg  (aliased: edge staging)
  __shared__ unsigned short bufQ[MPAD * HH];  // Q -> Hsum -> h2
  __shared__ int csr[EE];
  __shared__ int offs[NN + 1];
  __shared__ int cnt3[3][NN];
  __shared__ int base3[3][NN];
  __shared__ float bias[6][HH];               // bm1,bm2,bu1,bu2,gamma,beta

  const int tid  = threadIdx.x;
  const int lane = tid & 63;
  const int wave = tid >> 6;
  const int b    = blockIdx.x;

  int* edg = (int*)bufP;                      // overlay: used only before GEMM1

  // ---- stage: X fp32 + Xb bf16 (swizzled), edges, biases, zero-pad ----
  {
    const float4* nf4 = (const float4*)(node + (size_t)b * NN * HH);
    for (int i = tid; i < NN * HH / 4; i += 512) {
      float4 v = nf4[i];
      const int f = i * 4, r = f >> 7, c = f & 127;
      *(float4*)&X[r][c] = v;
      ushort4v pv = { f2b(v.x), f2b(v.y), f2b(v.z), f2b(v.w) };
      const unsigned byte = ((unsigned)(r * 256 + c * 2)) ^ ((unsigned)((r & 7) << 4));
      *(ushort4v*)((char*)Xb + byte) = pv;
    }
    for (int i = tid; i < (MPAD - NN) * 16; i += 512) {  // zero rows 81..95
      const int r = NN + i / 16, m = i % 16;
      const unsigned byte = ((unsigned)(r * 256 + m * 16)) ^ ((unsigned)((r & 7) << 4));
      ushort8v z = {0,0,0,0,0,0,0,0};
      *(ushort8v*)((char*)Xb + byte) = z;
    }
    for (int i = tid; i < 2 * EE; i += 512) edg[i] = eidx[i];
    if (tid < HH) {
      bias[0][tid] = bm1[tid]; bias[1][tid] = bm2[tid];
      bias[2][tid] = bu1[tid]; bias[3][tid] = bu2[tid];
      bias[4][tid] = gamma_[tid]; bias[5][tid] = beta_[tid];
    }
  }
  __syncthreads();

  // ---- deterministic CSR (stable counting sort by target) ----
  if (tid < 3 * NN) {
    const int t = tid % NN, ch = tid / NN;
    const int e0 = ch * CHUNK, e1 = e0 + CHUNK;
    int cnt = 0;
    for (int e = e0; e < e1; ++e) cnt += (edg[EE + e] == t);
    cnt3[ch][t] = cnt;
  }
  __syncthreads();
  if (tid == 0) {
    int run = 0;
    for (int t = 0; t < NN; ++t) {
      offs[t] = run;
      base3[0][t] = run;
      base3[1][t] = base3[0][t] + cnt3[0][t];
      base3[2][t] = base3[1][t] + cnt3[1][t];
      run = base3[2][t] + cnt3[2][t];
    }
    offs[NN] = run;
  }
  __syncthreads();
  if (tid < 3 * NN) {
    const int t = tid % NN, ch = tid / NN;
    const int e0 = ch * CHUNK, e1 = e0 + CHUNK;
    int pos = base3[ch][t];
    for (int e = e0; e < e1; ++e)
      if (edg[EE + e] == t) csr[pos++] = edg[e];
  }
  __syncthreads();

  // ---- wave -> tile mapping: 8 waves, each 2 N-tiles x 3 M-tiles ----
  const int nt0 = 2 * (wave & 3);
  const int mt0 = 3 * (wave >> 2);
  const int erow = (lane >> 4) * 4;   // C/D frag row base
  const int ecol = lane & 15;         // C/D frag col

  // ---- GEMM 1+2: P = Xb@Wm1t -> bufP ; Q = Xb@Wm1b -> bufQ ----
  {
    f32x4 accP[3][2], accQ[3][2];
#pragma unroll
    for (int mm = 0; mm < 3; ++mm)
#pragma unroll
      for (int nn = 0; nn < 2; ++nn) { accP[mm][nn] = (f32x4)0.f; accQ[mm][nn] = (f32x4)0.f; }
    gemm3x2(Xb, wpk + 0 * 16384, lane, mt0, nt0, accP);
    gemm3x2(Xb, wpk + 1 * 16384, lane, mt0, nt0, accQ);
#pragma unroll
    for (int mm = 0; mm < 3; ++mm)
#pragma unroll
      for (int nn = 0; nn < 2; ++nn)
#pragma unroll
        for (int rg = 0; rg < 4; ++rg) {
          const int R = (mt0 + mm) * 16 + erow + rg;
          const int C = (nt0 + nn) * 16 + ecol;
          const unsigned byte = ((unsigned)(R * 256 + C * 2)) ^ ((unsigned)((R & 7) << 4));
          const bool ok = (R < NN);
          *(unsigned short*)((char*)bufP + byte) = ok ? f2b(accP[mm][nn][rg]) : (unsigned short)0;
          *(unsigned short*)((char*)bufQ + byte) = ok ? f2b(accQ[mm][nn][rg]) : (unsigned short)0;
        }
  }
  __syncthreads();

  // ---- edge aggregation: Hsum[t] = sum relu(P[s] + Q[t] + bm1) -> bufQ ----
  for (int t = wave; t < NN; t += 8) {
    const unsigned qbyte = ((unsigned)(t * 256 + lane * 4)) ^ ((unsigned)((t & 7) << 4));
    const unsigned pq = *(const unsigned*)((const char*)bufQ + qbyte);
    const float q0 = b2f((unsigned short)(pq & 0xffff)) + bias[0][2 * lane];
    const float q1 = b2f((unsigned short)(pq >> 16))    + bias[0][2 * lane + 1];
    float h0 = 0.f, h1 = 0.f;
    const int o0 = offs[t], o1 = offs[t + 1];
    for (int e = o0; e < o1; ++e) {
      const int s = csr[e];
      const unsigned pb = ((unsigned)(s * 256 + lane * 4)) ^ ((unsigned)((s & 7) << 4));
      const unsigned pp = *(const unsigned*)((const char*)bufP + pb);
      h0 += fmaxf(b2f((unsigned short)(pp & 0xffff)) + q0, 0.f);
      h1 += fmaxf(b2f((unsigned short)(pp >> 16))    + q1, 0.f);
    }
    const unsigned hv = (unsigned)f2b(h0) | ((unsigned)f2b(h1) << 16);
    *(unsigned*)((char*)bufQ + qbyte) = hv;
  }
  __syncthreads();

  // ---- GEMM 4: agg = (Hsum@Wm2 + deg*bm2)/max(deg,1) -> bufP ----
  {
    f32x4 acc[3][2];
#pragma unroll
    for (int mm = 0; mm < 3; ++mm)
#pragma unroll
      for (int nn = 0; nn < 2; ++nn) acc[mm][nn] = (f32x4)0.f;
    gemm3x2(bufQ, wpk + 2 * 16384, lane, mt0, nt0, acc);
#pragma unroll
    for (int mm = 0; mm < 3; ++mm)
#pragma unroll
      for (int nn = 0; nn < 2; ++nn)
#pragma unroll
        for (int rg = 0; rg < 4; ++rg) {
          const int R = (mt0 + mm) * 16 + erow + rg;
          const int C = (nt0 + nn) * 16 + ecol;
          float v = 0.f;
          if (R < NN) {
            const float dg = (float)(offs[R + 1] - offs[R]);
            v = (acc[mm][nn][rg] + dg * bias[1][C]) * (1.f / fmaxf(dg, 1.f));
          }
          const unsigned byte = ((unsigned)(R * 256 + C * 2)) ^ ((unsigned)((R & 7) << 4));
          *(unsigned short*)((char*)bufP + byte) = f2b(v);
        }
  }
  __syncthreads();

  // ---- GEMM 5: h2 = relu(Xb@Wu1t + agg@Wu1b + bu1) -> bufQ ----
  {
    f32x4 acc[3][2];
#pragma unroll
    for (int mm = 0; mm < 3; ++mm)
#pragma unroll
      for (int nn = 0; nn < 2; ++nn) acc[mm][nn] = (f32x4)0.f;
    gemm3x2(Xb,   wpk + 3 * 16384, lane, mt0, nt0, acc);
    gemm3x2(bufP, wpk + 4 * 16384, lane, mt0, nt0, acc);
#pragma unroll
    for (int mm = 0; mm < 3; ++mm)
#pragma unroll
      for (int nn = 0; nn < 2; ++nn)
#pragma unroll
        for (int rg = 0; rg < 4; ++rg) {
          const int R = (mt0 + mm) * 16 + erow + rg;
          const int C = (nt0 + nn) * 16 + ecol;
          const float v = (R < NN) ? fmaxf(acc[mm][nn][rg] + bias[2][C], 0.f) : 0.f;
          const unsigned byte = ((unsigned)(R * 256 + C * 2)) ^ ((unsigned)((R & 7) << 4));
          *(unsigned short*)((char*)bufQ + byte) = f2b(v);
        }
  }
  __syncthreads();

  // ---- GEMM 6: x = X + h2@Wu2 + bu2 (in place into X fp32) ----
  {
    f32x4 acc[3][2];
#pragma unroll
    for (int mm = 0; mm < 3; ++mm)
#pragma unroll
      for (int nn = 0; nn < 2; ++nn) acc[mm][nn] = (f32x4)0.f;
    gemm3x2(bufQ, wpk + 5 * 16384, lane, mt0, nt0, acc);
#pragma unroll
    for (int mm = 0; mm < 3; ++mm)
#pragma unroll
      for (int nn = 0; nn < 2; ++nn)
#pragma unroll
        for (int rg = 0; rg < 4; ++rg) {
          const int R = (mt0 + mm) * 16 + erow + rg;
          const int C = (nt0 + nn) * 16 + ecol;
          if (R < NN) X[R][C] += acc[mm][nn][rg] + bias[3][C];
        }
  }
  __syncthreads();

  // ---- LayerNorm per row + store ----
  for (int r = wave; r < NN; r += 8) {
    const float x0 = X[r][lane], x1 = X[r][lane + 64];
    float s = x0 + x1;
#pragma unroll
    for (int off = 32; off; off >>= 1) s += __shfl_xor(s, off);
    const float mu = s * (1.f / 128.f);
    const float d0 = x0 - mu, d1 = x1 - mu;
    float v = d0 * d0 + d1 * d1;
#pragma unroll
    for (int off = 32; off; off >>= 1) v += __shfl_xor(v, off);
    const float rstd = rsqrtf(v * (1.f / 128.f) + 1e-5f);
    const size_t o = ((size_t)b * NN + r) * HH;
    out[o + lane]      = d0 * rstd * bias[4][lane]      + bias[5][lane];
    out[o + lane + 64] = d1 * rstd * bias[4][lane + 64] + bias[5][lane + 64];
  }
}

// ================= fp32 fallback (known-good) ===============================
__device__ __forceinline__ void gemm_acc_f32(const float (*A)[HH], const float* __restrict__ Wg,
                                             int c, int row0, int nr, float (&acc)[41]) {
  float w[8];
#pragma unroll
  for (int j = 0; j < 8; ++j) w[j] = Wg[j * HH + c];
  for (int k0 = 0; k0 < HH; k0 += 8) {
    float wn[8];
    if (k0 + 8 < HH) {
#pragma unroll
      for (int j = 0; j < 8; ++j) wn[j] = Wg[(k0 + 8 + j) * HH + c];
    }
#pragma unroll
    for (int i = 0; i < 41; ++i) {
      if (i < nr) {
        const float4 a0 = *(const float4*)&A[row0 + i][k0];
        const float4 a1 = *(const float4*)&A[row0 + i][k0 + 4];
        acc[i] += a0.x * w[0] + a0.y * w[1] + a0.z * w[2] + a0.w * w[3]
                + a1.x * w[4] + a1.y * w[5] + a1.z * w[6] + a1.w * w[7];
      }
    }
#pragma unroll
    for (int j = 0; j < 8; ++j) w[j] = wn[j];
  }
}

__global__ __launch_bounds__(256, 1)
void mpnn_fused_kernel(const float* __restrict__ node, const int* __restrict__ eidx,
                       const float* __restrict__ Wm1, const float* __restrict__ bm1,
                       const float* __restrict__ Wm2, const float* __restrict__ bm2,
                       const float* __restrict__ Wu1, const float* __restrict__ bu1,
                       const float* __restrict__ Wu2, const float* __restrict__ bu2,
                       const float* __restrict__ gamma_, const float* __restrict__ beta_,
                       float* __restrict__ out) {
  __shared__ float X[NN][HH];
  __shared__ float Pb[NN][HH];
  __shared__ float Qb[NN][HH];
  __shared__ int   edg[2 * EE];
  __shared__ int   csr[EE];
  __shared__ int   offs[NN + 1];
  __shared__ int   cnt3[3][NN];
  __shared__ int   base3[3][NN];
  __shared__ float biases[6][HH];

  const int tid  = threadIdx.x;
  const int lane = tid & 63;
  const int wave = tid >> 6;
  const int b    = blockIdx.x;

  {
    const float4* nf4 = (const float4*)(node + (size_t)b * NN * HH);
    float4* X4 = (float4*)&X[0][0];
    for (int i = tid; i < NN * HH / 4; i += 256) X4[i] = nf4[i];
    for (int i = tid; i < 2 * EE; i += 256) edg[i] = eidx[i];
    if (tid < HH) {
      biases[0][tid] = bm1[tid]; biases[1][tid] = bm2[tid];
      biases[2][tid] = bu1[tid]; biases[3][tid] = bu2[tid];
      biases[4][tid] = gamma_[tid]; biases[5][tid] = beta_[tid];
    }
  }
  __syncthreads();
  if (tid < 3 * NN) {
    const int t = tid % NN, ch = tid / NN;
    const int e0 = ch * CHUNK, e1 = e0 + CHUNK;
    int cnt = 0;
    for (int e = e0; e < e1; ++e) cnt += (edg[EE + e] == t);
    cnt3[ch][t] = cnt;
  }
  __syncthreads();
  if (tid == 0) {
    int run = 0;
    for (int t = 0; t < NN; ++t) {
      offs[t] = run;
      base3[0][t] = run;
      base3[1][t] = base3[0][t] + cnt3[0][t];
      base3[2][t] = base3[1][t] + cnt3[1][t];
      run = base3[2][t] + cnt3[2][t];
    }
    offs[NN] = run;
  }
  __syncthreads();
  if (tid < 3 * NN) {
    const int t = tid % NN, ch = tid / NN;
    const int e0 = ch * CHUNK, e1 = e0 + CHUNK;
    int pos = base3[ch][t];
    for (int e = e0; e < e1; ++e)
      if (edg[EE + e] == t) csr[pos++] = edg[e];
  }
  __syncthreads();

  const int c    = ((wave & 1) << 6) | lane;
  const int row0 = (wave >> 1) ? 41 : 0;
  const int nr   = (wave >> 1) ? 40 : 41;

  {
    float acc[41];
#pragma unroll
    for (int i = 0; i < 41; ++i) acc[i] = 0.f;
    gemm_acc_f32(X, Wm1, c, row0, nr, acc);
#pragma unroll
    for (int i = 0; i < 41; ++i) if (i < nr) Pb[row0 + i][c] = acc[i];
  }
  {
    float acc[41];
#pragma unroll
    for (int i = 0; i < 41; ++i) acc[i] = 0.f;
    gemm_acc_f32(X, Wm1 + HH * HH, c, row0, nr, acc);
#pragma unroll
    for (int i = 0; i < 41; ++i) if (i < nr) Qb[row0 + i][c] = acc[i];
  }
  __syncthreads();

  for (int t = wave; t < NN; t += 4) {
    const int o0 = offs[t], o1 = offs[t + 1];
    const float q0 = Qb[t][lane]      + biases[0][lane];
    const float q1 = Qb[t][lane + 64] + biases[0][lane + 64];
    float h0 = 0.f, h1 = 0.f;
    for (int e = o0; e < o1; ++e) {
      const int s = csr[e];
      h0 += fmaxf(Pb[s][lane]      + q0, 0.f);
      h1 += fmaxf(Pb[s][lane + 64] + q1, 0.f);
    }
    Qb[t][lane]      = h0;
    Qb[t][lane + 64] = h1;
  }
  __syncthreads();

  {
    float acc[41];
#pragma unroll
    for (int i = 0; i < 41; ++i) acc[i] = 0.f;
    gemm_acc_f32(Qb, Wm2, c, row0, nr, acc);
#pragma unroll
    for (int i = 0; i < 41; ++i) if (i < nr) {
      const int r = row0 + i;
      const float d = (float)(offs[r + 1] - offs[r]);
      Pb[r][c] = (acc[i] + d * biases[1][c]) * (1.f / fmaxf(d, 1.f));
    }
  }
  __syncthreads();

  {
    float acc[41];
#pragma unroll
    for (int i = 0; i < 41; ++i) acc[i] = 0.f;
    gemm_acc_f32(X,  Wu1,           c, row0, nr, acc);
    gemm_acc_f32(Pb, Wu1 + HH * HH, c, row0, nr, acc);
#pragma unroll
    for (int i = 0; i < 41; ++i) if (i < nr)
      Qb[row0 + i][c] = fmaxf(acc[i] + biases[2][c], 0.f);
  }
  __syncthreads();

  {
    float acc[41];
#pragma unroll
    for (int i = 0; i < 41; ++i) acc[i] = 0.f;
    gemm_acc_f32(Qb, Wu2, c, row0, nr, acc);
#pragma unroll
    for (int i = 0; i < 41; ++i) if (i < nr) {
      const int r = row0 + i;
      X[r][c] = X[r][c] + acc[i] + biases[3][c];
    }
  }
  __syncthreads();

  for (int r = wave; r < NN; r += 4) {
    const float x0 = X[r][lane], x1 = X[r][lane + 64];
    float s = x0 + x1;
#pragma unroll
    for (int off = 32; off; off >>= 1) s += __shfl_xor(s, off);
    const float mu = s * (1.f / 128.f);
    const float d0 = x0 - mu, d1 = x1 - mu;
    float v = d0 * d0 + d1 * d1;
#pragma unroll
    for (int off = 32; off; off >>= 1) v += __shfl_xor(v, off);
    const float rstd = rsqrtf(v * (1.f / 128.f) + 1e-5f);
    const size_t o = ((size_t)b * NN + r) * HH;
    out[o + lane]      = d0 * rstd * biases[4][lane]      + biases[5][lane];
    out[o + lane + 64] = d1 * rstd * biases[4][lane + 64] + biases[5][lane + 64];
  }
}

extern "C" void kernel_launch(void* const* d_in, const int* in_sizes, int n_in,
                              void* d_out, int out_size, void* d_ws, size_t ws_size,
                              hipStream_t stream) {
  (void)in_sizes; (void)n_in; (void)out_size;
  const float* node  = (const float*)d_in[0];
  const int*   eidx  = (const int*)  d_in[1];
  const float* Wm1   = (const float*)d_in[2];
  const float* bm1   = (const float*)d_in[3];
  const float* Wm2   = (const float*)d_in[4];
  const float* bm2   = (const float*)d_in[5];
  const float* Wu1   = (const float*)d_in[6];
  const float* bu1   = (const float*)d_in[7];
  const float* Wu2   = (const float*)d_in[8];
  const float* bu2   = (const float*)d_in[9];
  const float* gamma_= (const float*)d_in[10];
  const float* beta_ = (const float*)d_in[11];
  float* outp = (float*)d_out;

  const size_t need = (size_t)6 * 16384 * sizeof(unsigned short);  // 196608 B
  if (ws_size >= need) {
    unsigned short* wpk = (unsigned short*)d_ws;
    hipLaunchKernelGGL(pack_weights_kernel, dim3(48), dim3(256), 0, stream,
                       Wm1, Wm2, Wu1, Wu2, wpk);
    hipLaunchKernelGGL(mpnn_mfma_kernel, dim3(256), dim3(512), 0, stream,
                       node, eidx, bm1, bm2, bu1, bu2, gamma_, beta_, wpk, outp);
  } else {
    hipLaunchKernelGGL(mpnn_fused_kernel, dim3(256), dim3(256), 0, stream,
                       node, eidx, Wm1, bm1, Wm2, bm2, Wu1, bu1, Wu2, bu2,
                       gamma_, beta_, outp);
  }
}

// Round 3
// 77.168 us; speedup vs baseline: 3.0529x; 1.2269x over previous
//
#include <hip/hip_runtime.h>

// Fused MPNN layer, B=256, N=81, H=128, E=1620 — MFMA bf16, CSR hoisted.
//   P = X @ Wm1[:H],  Q = X @ Wm1[H:]
//   Hsum[t] = sum_{e: tgt=t} relu(P[src_e] + Q[t] + bm1)
//   agg[t]  = (Hsum[t] @ Wm2 + deg_t*bm2) / max(deg_t,1)
//   h2 = relu(X @ Wu1[:H] + agg @ Wu1[H:] + bu1)
//   x  = X + h2 @ Wu2 + bu2 ;  out = LayerNorm(x)*gamma + beta
// Kernel 1 (grid 49): blocks 0-47 pack weights to bf16 MFMA-frag order in d_ws;
//                     block 48 builds deterministic CSR (stable 3-chunk sort) in d_ws.
// Kernel 2 (grid 256, 1024 thr = 16 waves): whole layer per batch in LDS.

#define NN 81
#define HH 128
#define EE 1620
#define CHUNK 540
#define MPAD 96
#define WB_BYTES 196608                 // 6 * 16384 ushorts
#define OFFS_OFF (WB_BYTES)             // int offs[82]
#define CSR_OFF  (WB_BYTES + 82 * 4)    // int csr[1620]
#define WS_NEED  (CSR_OFF + EE * 4)

typedef __attribute__((ext_vector_type(8))) short bf16x8;
typedef __attribute__((ext_vector_type(8))) unsigned short ushort8v;
typedef __attribute__((ext_vector_type(4))) unsigned short ushort4v;
typedef __attribute__((ext_vector_type(4))) float f32x4;

__device__ __forceinline__ unsigned short f2b(float f) {
  union { float f; unsigned u; } v; v.f = f;
  unsigned r = v.u + 0x7fffu + ((v.u >> 16) & 1u);
  return (unsigned short)(r >> 16);
}
__device__ __forceinline__ float b2f(unsigned short h) {
  union { unsigned u; float f; } v; v.u = ((unsigned)h) << 16;
  return v.f;
}

// ---------------- setup kernel: weight pack (blocks 0-47) + CSR (block 48) ----
__global__ __launch_bounds__(256)
void setup_kernel(const float* __restrict__ Wm1, const float* __restrict__ Wm2,
                  const float* __restrict__ Wu1, const float* __restrict__ Wu2,
                  const int* __restrict__ eidx, char* __restrict__ ws) {
  __shared__ int edg[2 * EE];
  __shared__ int cnt3[3][NN];
  __shared__ int base3[3][NN];
  __shared__ int offsS[NN + 1];
  __shared__ int csrS[EE];

  if (blockIdx.x < 48) {
    const int gid = blockIdx.x * 256 + threadIdx.x;
    if (gid >= 6 * 8 * 4 * 64) return;
    const int lane = gid & 63;
    const int t = gid >> 6;
    const int ks = t & 3, nt = (t >> 2) & 7, mat = t >> 5;
    const float* src;
    if (mat == 0) src = Wm1;
    else if (mat == 1) src = Wm1 + HH * HH;
    else if (mat == 2) src = Wm2;
    else if (mat == 3) src = Wu1;
    else if (mat == 4) src = Wu1 + HH * HH;
    else src = Wu2;
    const int c = nt * 16 + (lane & 15);
    const int k0 = ks * 32 + (lane >> 4) * 8;
    bf16x8 pv;
#pragma unroll
    for (int j = 0; j < 8; ++j) pv[j] = (short)f2b(src[(k0 + j) * HH + c]);
    *(bf16x8*)((unsigned short*)ws + (size_t)mat * 16384 + (((nt * 4 + ks) * 64) + lane) * 8) = pv;
    return;
  }

  // ---- block 48: deterministic CSR (stable counting sort by target) ----
  const int tid = threadIdx.x;
  for (int i = tid; i < 2 * EE; i += 256) edg[i] = eidx[i];
  __syncthreads();
  if (tid < 3 * NN) {
    const int t = tid % NN, ch = tid / NN;
    const int e0 = ch * CHUNK, e1 = e0 + CHUNK;
    int cnt = 0;
    for (int e = e0; e < e1; ++e) cnt += (edg[EE + e] == t);
    cnt3[ch][t] = cnt;
  }
  __syncthreads();
  if (tid == 0) {
    int run = 0;
    for (int t = 0; t < NN; ++t) {
      offsS[t] = run;
      base3[0][t] = run;
      base3[1][t] = base3[0][t] + cnt3[0][t];
      base3[2][t] = base3[1][t] + cnt3[1][t];
      run = base3[2][t] + cnt3[2][t];
    }
    offsS[NN] = run;
  }
  __syncthreads();
  if (tid < 3 * NN) {
    const int t = tid % NN, ch = tid / NN;
    const int e0 = ch * CHUNK, e1 = e0 + CHUNK;
    int pos = base3[ch][t];
    for (int e = e0; e < e1; ++e)
      if (edg[EE + e] == t) csrS[pos++] = edg[e];
  }
  __syncthreads();
  int* wofs = (int*)(ws + OFFS_OFF);
  int* wcsr = (int*)(ws + CSR_OFF);
  for (int i = tid; i < NN + 1; i += 256) wofs[i] = offsS[i];
  for (int i = tid; i < EE; i += 256) wcsr[i] = csrS[i];
}

// ---------------- MFMA tile GEMM helpers (per wave: 3 M-tiles x 1 N-tile) -----
__device__ __forceinline__ void gemm3x1(const unsigned short* Ab, const unsigned short* Wp,
                                        int lane, int mt0, int nt0, f32x4 acc[3]) {
  bf16x8 Bf[4];
#pragma unroll
  for (int ks = 0; ks < 4; ++ks)
    Bf[ks] = *(const bf16x8*)(Wp + ((nt0 * 4 + ks) * 64 + lane) * 8);
  const int rl = lane & 15;
  const int kb = (lane >> 4) * 16;
  const unsigned swz = (unsigned)((rl & 7) << 4);
#pragma unroll
  for (int ks = 0; ks < 4; ++ks)
#pragma unroll
    for (int mm = 0; mm < 3; ++mm) {
      const int r = (mt0 + mm) * 16 + rl;
      const unsigned byte = (unsigned)(r * 256) + (((unsigned)(ks * 64 + kb)) ^ swz);
      bf16x8 a = *(const bf16x8*)((const char*)Ab + byte);
      acc[mm] = __builtin_amdgcn_mfma_f32_16x16x32_bf16(a, Bf[ks], acc[mm], 0, 0, 0);
    }
}

// dual-B: same A, two packed matrices (saves the A re-read)
__device__ __forceinline__ void gemm3x1x2(const unsigned short* Ab,
                                          const unsigned short* Wp0, const unsigned short* Wp1,
                                          int lane, int mt0, int nt0,
                                          f32x4 acc0[3], f32x4 acc1[3]) {
  bf16x8 B0[4], B1[4];
#pragma unroll
  for (int ks = 0; ks < 4; ++ks) {
    B0[ks] = *(const bf16x8*)(Wp0 + ((nt0 * 4 + ks) * 64 + lane) * 8);
    B1[ks] = *(const bf16x8*)(Wp1 + ((nt0 * 4 + ks) * 64 + lane) * 8);
  }
  const int rl = lane & 15;
  const int kb = (lane >> 4) * 16;
  const unsigned swz = (unsigned)((rl & 7) << 4);
#pragma unroll
  for (int ks = 0; ks < 4; ++ks)
#pragma unroll
    for (int mm = 0; mm < 3; ++mm) {
      const int r = (mt0 + mm) * 16 + rl;
      const unsigned byte = (unsigned)(r * 256) + (((unsigned)(ks * 64 + kb)) ^ swz);
      bf16x8 a = *(const bf16x8*)((const char*)Ab + byte);
      acc0[mm] = __builtin_amdgcn_mfma_f32_16x16x32_bf16(a, B0[ks], acc0[mm], 0, 0, 0);
      acc1[mm] = __builtin_amdgcn_mfma_f32_16x16x32_bf16(a, B1[ks], acc1[mm], 0, 0, 0);
    }
}

__global__ __launch_bounds__(1024, 4)
void mpnn_mfma2_kernel(const float* __restrict__ node,
                       const float* __restrict__ bm1, const float* __restrict__ bm2,
                       const float* __restrict__ bu1, const float* __restrict__ bu2,
                       const float* __restrict__ gamma_, const float* __restrict__ beta_,
                       const char* __restrict__ ws,
                       float* __restrict__ out) {
  __shared__ float X[NN][HH];                 // fp32 for residual + LN
  __shared__ unsigned short Xb[MPAD * HH];    // swizzled bf16
  __shared__ unsigned short bufP[MPAD * HH];  // P -> agg
  __shared__ unsigned short bufQ[MPAD * HH];  // Q -> Hsum -> h2
  __shared__ int   csrL[EE];
  __shared__ int   offsL[NN + 1];
  __shared__ float bias[6][HH];               // bm1,bm2,bu1,bu2,gamma,beta

  const int tid  = threadIdx.x;
  const int lane = tid & 63;
  const int wave = tid >> 6;     // 0..15
  const int b    = blockIdx.x;

  const unsigned short* wpk = (const unsigned short*)ws;
  const int* wofs = (const int*)(ws + OFFS_OFF);
  const int* wcsr = (const int*)(ws + CSR_OFF);

  // ---- stage: X fp32 + Xb bf16 (swizzled), csr/offs, biases, zero-pad ----
  {
    const float4* nf4 = (const float4*)(node + (size_t)b * NN * HH);
    for (int i = tid; i < NN * HH / 4; i += 1024) {
      float4 v = nf4[i];
      const int f = i * 4, r = f >> 7, c = f & 127;
      *(float4*)&X[r][c] = v;
      ushort4v pv = { f2b(v.x), f2b(v.y), f2b(v.z), f2b(v.w) };
      const unsigned byte = ((unsigned)(r * 256 + c * 2)) ^ ((unsigned)((r & 7) << 4));
      *(ushort4v*)((char*)Xb + byte) = pv;
    }
    if (tid < (MPAD - NN) * 16) {   // zero rows 81..95
      const int r = NN + tid / 16, m = tid % 16;
      const unsigned byte = ((unsigned)(r * 256 + m * 16)) ^ ((unsigned)((r & 7) << 4));
      ushort8v z = {0,0,0,0,0,0,0,0};
      *(ushort8v*)((char*)Xb + byte) = z;
    }
    for (int i = tid; i < EE; i += 1024) csrL[i] = wcsr[i];
    if (tid < NN + 1) offsL[tid] = wofs[tid];
    if (tid < HH) {
      bias[0][tid] = bm1[tid]; bias[1][tid] = bm2[tid];
      bias[2][tid] = bu1[tid]; bias[3][tid] = bu2[tid];
      bias[4][tid] = gamma_[tid]; bias[5][tid] = beta_[tid];
    }
  }
  __syncthreads();

  // ---- wave tile map: 16 waves = 8 N-tiles x 2 M-halves (3 M-tiles each) ----
  const int nt0 = wave & 7;
  const int mt0 = 3 * (wave >> 3);
  const int erow = (lane >> 4) * 4;
  const int ecol = lane & 15;

  // ---- GEMM 1+2: P = Xb@Wm1t -> bufP ; Q = Xb@Wm1b -> bufQ ----
  {
    f32x4 accP[3], accQ[3];
#pragma unroll
    for (int mm = 0; mm < 3; ++mm) { accP[mm] = (f32x4)0.f; accQ[mm] = (f32x4)0.f; }
    gemm3x1x2(Xb, wpk, wpk + 16384, lane, mt0, nt0, accP, accQ);
#pragma unroll
    for (int mm = 0; mm < 3; ++mm)
#pragma unroll
      for (int rg = 0; rg < 4; ++rg) {
        const int R = (mt0 + mm) * 16 + erow + rg;
        const int C = nt0 * 16 + ecol;
        const unsigned byte = ((unsigned)(R * 256 + C * 2)) ^ ((unsigned)((R & 7) << 4));
        const bool ok = (R < NN);
        *(unsigned short*)((char*)bufP + byte) = ok ? f2b(accP[mm][rg]) : (unsigned short)0;
        *(unsigned short*)((char*)bufQ + byte) = ok ? f2b(accQ[mm][rg]) : (unsigned short)0;
      }
  }
  __syncthreads();

  // ---- edge aggregation: Hsum[t] = sum relu(P[s] + Q[t] + bm1) -> bufQ ----
  {
    const float bm1a = bias[0][2 * lane];
    const float bm1b = bias[0][2 * lane + 1];
    for (int t = wave; t < NN; t += 16) {
      const unsigned qbyte = ((unsigned)(t * 256 + lane * 4)) ^ ((unsigned)((t & 7) << 4));
      const unsigned pq = *(const unsigned*)((const char*)bufQ + qbyte);
      const float q0 = b2f((unsigned short)(pq & 0xffff)) + bm1a;
      const float q1 = b2f((unsigned short)(pq >> 16))    + bm1b;
      float h0 = 0.f, h1 = 0.f;
      const int o0 = offsL[t], o1 = offsL[t + 1];
      for (int e = o0; e < o1; ++e) {
        const int s = csrL[e];
        const unsigned pb = ((unsigned)(s * 256 + lane * 4)) ^ ((unsigned)((s & 7) << 4));
        const unsigned pp = *(const unsigned*)((const char*)bufP + pb);
        h0 += fmaxf(b2f((unsigned short)(pp & 0xffff)) + q0, 0.f);
        h1 += fmaxf(b2f((unsigned short)(pp >> 16))    + q1, 0.f);
      }
      const unsigned hv = (unsigned)f2b(h0) | ((unsigned)f2b(h1) << 16);
      *(unsigned*)((char*)bufQ + qbyte) = hv;
    }
  }
  __syncthreads();

  // ---- GEMM 4: agg = (Hsum@Wm2 + deg*bm2)/max(deg,1) -> bufP ----
  {
    f32x4 acc[3];
#pragma unroll
    for (int mm = 0; mm < 3; ++mm) acc[mm] = (f32x4)0.f;
    gemm3x1(bufQ, wpk + 2 * 16384, lane, mt0, nt0, acc);
#pragma unroll
    for (int mm = 0; mm < 3; ++mm)
#pragma unroll
      for (int rg = 0; rg < 4; ++rg) {
        const int R = (mt0 + mm) * 16 + erow + rg;
        const int C = nt0 * 16 + ecol;
        float v = 0.f;
        if (R < NN) {
          const float dg = (float)(offsL[R + 1] - offsL[R]);
          v = (acc[mm][rg] + dg * bias[1][C]) * (1.f / fmaxf(dg, 1.f));
        }
        const unsigned byte = ((unsigned)(R * 256 + C * 2)) ^ ((unsigned)((R & 7) << 4));
        *(unsigned short*)((char*)bufP + byte) = f2b(v);
      }
  }
  __syncthreads();

  // ---- GEMM 5: h2 = relu(Xb@Wu1t + agg@Wu1b + bu1) -> bufQ ----
  {
    f32x4 acc[3];
#pragma unroll
    for (int mm = 0; mm < 3; ++mm) acc[mm] = (f32x4)0.f;
    gemm3x1(Xb,   wpk + 3 * 16384, lane, mt0, nt0, acc);
    gemm3x1(bufP, wpk + 4 * 16384, lane, mt0, nt0, acc);
#pragma unroll
    for (int mm = 0; mm < 3; ++mm)
#pragma unroll
      for (int rg = 0; rg < 4; ++rg) {
        const int R = (mt0 + mm) * 16 + erow + rg;
        const int C = nt0 * 16 + ecol;
        const float v = (R < NN) ? fmaxf(acc[mm][rg] + bias[2][C], 0.f) : 0.f;
        const unsigned byte = ((unsigned)(R * 256 + C * 2)) ^ ((unsigned)((R & 7) << 4));
        *(unsigned short*)((char*)bufQ + byte) = f2b(v);
      }
  }
  __syncthreads();

  // ---- GEMM 6: x = X + h2@Wu2 + bu2 (in place into X fp32) ----
  {
    f32x4 acc[3];
#pragma unroll
    for (int mm = 0; mm < 3; ++mm) acc[mm] = (f32x4)0.f;
    gemm3x1(bufQ, wpk + 5 * 16384, lane, mt0, nt0, acc);
#pragma unroll
    for (int mm = 0; mm < 3; ++mm)
#pragma unroll
      for (int rg = 0; rg < 4; ++rg) {
        const int R = (mt0 + mm) * 16 + erow + rg;
        const int C = nt0 * 16 + ecol;
        if (R < NN) X[R][C] += acc[mm][rg] + bias[3][C];
      }
  }
  __syncthreads();

  // ---- LayerNorm per row + store ----
  for (int r = wave; r < NN; r += 16) {
    const float x0 = X[r][lane], x1 = X[r][lane + 64];
    float s = x0 + x1;
#pragma unroll
    for (int off = 32; off; off >>= 1) s += __shfl_xor(s, off);
    const float mu = s * (1.f / 128.f);
    const float d0 = x0 - mu, d1 = x1 - mu;
    float v = d0 * d0 + d1 * d1;
#pragma unroll
    for (int off = 32; off; off >>= 1) v += __shfl_xor(v, off);
    const float rstd = rsqrtf(v * (1.f / 128.f) + 1e-5f);
    const size_t o = ((size_t)b * NN + r) * HH;
    out[o + lane]      = d0 * rstd * bias[4][lane]      + bias[5][lane];
    out[o + lane + 64] = d1 * rstd * bias[4][lane + 64] + bias[5][lane + 64];
  }
}

// ================= fp32 fallback (known-good, used only if ws too small) =====
__device__ __forceinline__ void gemm_acc_f32(const float (*A)[HH], const float* __restrict__ Wg,
                                             int c, int row0, int nr, float (&acc)[41]) {
  float w[8];
#pragma unroll
  for (int j = 0; j < 8; ++j) w[j] = Wg[j * HH + c];
  for (int k0 = 0; k0 < HH; k0 += 8) {
    float wn[8];
    if (k0 + 8 < HH) {
#pragma unroll
      for (int j = 0; j < 8; ++j) wn[j] = Wg[(k0 + 8 + j) * HH + c];
    }
#pragma unroll
    for (int i = 0; i < 41; ++i) {
      if (i < nr) {
        const float4 a0 = *(const float4*)&A[row0 + i][k0];
        const float4 a1 = *(const float4*)&A[row0 + i][k0 + 4];
        acc[i] += a0.x * w[0] + a0.y * w[1] + a0.z * w[2] + a0.w * w[3]
                + a1.x * w[4] + a1.y * w[5] + a1.z * w[6] + a1.w * w[7];
      }
    }
#pragma unroll
    for (int j = 0; j < 8; ++j) w[j] = wn[j];
  }
}

__global__ __launch_bounds__(256, 1)
void mpnn_fused_kernel(const float* __restrict__ node, const int* __restrict__ eidx,
                       const float* __restrict__ Wm1, const float* __restrict__ bm1,
                       const float* __restrict__ Wm2, const float* __restrict__ bm2,
                       const float* __restrict__ Wu1, const float* __restrict__ bu1,
                       const float* __restrict__ Wu2, const float* __restrict__ bu2,
                       const float* __restrict__ gamma_, const float* __restrict__ beta_,
                       float* __restrict__ out) {
  __shared__ float X[NN][HH];
  __shared__ float Pb[NN][HH];
  __shared__ float Qb[NN][HH];
  __shared__ int   edg[2 * EE];
  __shared__ int   csr[EE];
  __shared__ int   offs[NN + 1];
  __shared__ int   cnt3[3][NN];
  __shared__ int   base3[3][NN];
  __shared__ float biases[6][HH];

  const int tid  = threadIdx.x;
  const int lane = tid & 63;
  const int wave = tid >> 6;
  const int b    = blockIdx.x;

  {
    const float4* nf4 = (const float4*)(node + (size_t)b * NN * HH);
    float4* X4 = (float4*)&X[0][0];
    for (int i = tid; i < NN * HH / 4; i += 256) X4[i] = nf4[i];
    for (int i = tid; i < 2 * EE; i += 256) edg[i] = eidx[i];
    if (tid < HH) {
      biases[0][tid] = bm1[tid]; biases[1][tid] = bm2[tid];
      biases[2][tid] = bu1[tid]; biases[3][tid] = bu2[tid];
      biases[4][tid] = gamma_[tid]; biases[5][tid] = beta_[tid];
    }
  }
  __syncthreads();
  if (tid < 3 * NN) {
    const int t = tid % NN, ch = tid / NN;
    const int e0 = ch * CHUNK, e1 = e0 + CHUNK;
    int cnt = 0;
    for (int e = e0; e < e1; ++e) cnt += (edg[EE + e] == t);
    cnt3[ch][t] = cnt;
  }
  __syncthreads();
  if (tid == 0) {
    int run = 0;
    for (int t = 0; t < NN; ++t) {
      offs[t] = run;
      base3[0][t] = run;
      base3[1][t] = base3[0][t] + cnt3[0][t];
      base3[2][t] = base3[1][t] + cnt3[1][t];
      run = base3[2][t] + cnt3[2][t];
    }
    offs[NN] = run;
  }
  __syncthreads();
  if (tid < 3 * NN) {
    const int t = tid % NN, ch = tid / NN;
    const int e0 = ch * CHUNK, e1 = e0 + CHUNK;
    int pos = base3[ch][t];
    for (int e = e0; e < e1; ++e)
      if (edg[EE + e] == t) csr[pos++] = edg[e];
  }
  __syncthreads();

  const int c    = ((wave & 1) << 6) | lane;
  const int row0 = (wave >> 1) ? 41 : 0;
  const int nr   = (wave >> 1) ? 40 : 41;

  {
    float acc[41];
#pragma unroll
    for (int i = 0; i < 41; ++i) acc[i] = 0.f;
    gemm_acc_f32(X, Wm1, c, row0, nr, acc);
#pragma unroll
    for (int i = 0; i < 41; ++i) if (i < nr) Pb[row0 + i][c] = acc[i];
  }
  {
    float acc[41];
#pragma unroll
    for (int i = 0; i < 41; ++i) acc[i] = 0.f;
    gemm_acc_f32(X, Wm1 + HH * HH, c, row0, nr, acc);
#pragma unroll
    for (int i = 0; i < 41; ++i) if (i < nr) Qb[row0 + i][c] = acc[i];
  }
  __syncthreads();

  for (int t = wave; t < NN; t += 4) {
    const int o0 = offs[t], o1 = offs[t + 1];
    const float q0 = Qb[t][lane]      + biases[0][lane];
    const float q1 = Qb[t][lane + 64] + biases[0][lane + 64];
    float h0 = 0.f, h1 = 0.f;
    for (int e = o0; e < o1; ++e) {
      const int s = csr[e];
      h0 += fmaxf(Pb[s][lane]      + q0, 0.f);
      h1 += fmaxf(Pb[s][lane + 64] + q1, 0.f);
    }
    Qb[t][lane]      = h0;
    Qb[t][lane + 64] = h1;
  }
  __syncthreads();

  {
    float acc[41];
#pragma unroll
    for (int i = 0; i < 41; ++i) acc[i] = 0.f;
    gemm_acc_f32(Qb, Wm2, c, row0, nr, acc);
#pragma unroll
    for (int i = 0; i < 41; ++i) if (i < nr) {
      const int r = row0 + i;
      const float d = (float)(offs[r + 1] - offs[r]);
      Pb[r][c] = (acc[i] + d * biases[1][c]) * (1.f / fmaxf(d, 1.f));
    }
  }
  __syncthreads();

  {
    float acc[41];
#pragma unroll
    for (int i = 0; i < 41; ++i) acc[i] = 0.f;
    gemm_acc_f32(X,  Wu1,           c, row0, nr, acc);
    gemm_acc_f32(Pb, Wu1 + HH * HH, c, row0, nr, acc);
#pragma unroll
    for (int i = 0; i < 41; ++i) if (i < nr)
      Qb[row0 + i][c] = fmaxf(acc[i] + biases[2][c], 0.f);
  }
  __syncthreads();

  {
    float acc[41];
#pragma unroll
    for (int i = 0; i < 41; ++i) acc[i] = 0.f;
    gemm_acc_f32(Qb, Wu2, c, row0, nr, acc);
#pragma unroll
    for (int i = 0; i < 41; ++i) if (i < nr) {
      const int r = row0 + i;
      X[r][c] = X[r][c] + acc[i] + biases[3][c];
    }
  }
  __syncthreads();

  for (int r = wave; r < NN; r += 4) {
    const float x0 = X[r][lane], x1 = X[r][lane + 64];
    float s = x0 + x1;
#pragma unroll
    for (int off = 32; off; off >>= 1) s += __shfl_xor(s, off);
    const float mu = s * (1.f / 128.f);
    const float d0 = x0 - mu, d1 = x1 - mu;
    float v = d0 * d0 + d1 * d1;
#pragma unroll
    for (int off = 32; off; off >>= 1) v += __shfl_xor(v, off);
    const float rstd = rsqrtf(v * (1.f / 128.f) + 1e-5f);
    const size_t o = ((size_t)b * NN + r) * HH;
    out[o + lane]      = d0 * rstd * biases[4][lane]      + biases[5][lane];
    out[o + lane + 64] = d1 * rstd * biases[4][lane + 64] + biases[5][lane + 64];
  }
}

extern "C" void kernel_launch(void* const* d_in, const int* in_sizes, int n_in,
                              void* d_out, int out_size, void* d_ws, size_t ws_size,
                              hipStream_t stream) {
  (void)in_sizes; (void)n_in; (void)out_size;
  const float* node  = (const float*)d_in[0];
  const int*   eidx  = (const int*)  d_in[1];
  const float* Wm1   = (const float*)d_in[2];
  const float* bm1   = (const float*)d_in[3];
  const float* Wm2   = (const float*)d_in[4];
  const float* bm2   = (const float*)d_in[5];
  const float* Wu1   = (const float*)d_in[6];
  const float* bu1   = (const float*)d_in[7];
  const float* Wu2   = (const float*)d_in[8];
  const float* bu2   = (const float*)d_in[9];
  const float* gamma_= (const float*)d_in[10];
  const float* beta_ = (const float*)d_in[11];
  float* outp = (float*)d_out;

  if (ws_size >= (size_t)WS_NEED) {
    char* ws = (char*)d_ws;
    hipLaunchKernelGGL(setup_kernel, dim3(49), dim3(256), 0, stream,
                       Wm1, Wm2, Wu1, Wu2, eidx, ws);
    hipLaunchKernelGGL(mpnn_mfma2_kernel, dim3(256), dim3(1024), 0, stream,
                       node, bm1, bm2, bu1, bu2, gamma_, beta_, ws, outp);
  } else {
    hipLaunchKernelGGL(mpnn_fused_kernel, dim3(256), dim3(256), 0, stream,
                       node, eidx, Wm1, bm1, Wm2, bm2, Wu1, bu1, Wu2, bu2,
                       gamma_, beta_, outp);
  }
}

// Round 4
// 46.962 us; speedup vs baseline: 5.0166x; 1.6432x over previous
//
#include <hip/hip_runtime.h>

// Fused MPNN layer, B=256, N=81, H=128, E=1620 — MFMA bf16.
//   P = X @ Wm1[:H],  Q = X @ Wm1[H:]
//   Hsum[t] = sum_{e: tgt=t} relu(P[src_e] + Q[t] + bm1)
//   agg[t]  = (Hsum[t] @ Wm2 + deg_t*bm2) / max(deg_t,1)
//   h2 = relu(X @ Wu1[:H] + agg @ Wu1[H:] + bu1)
//   x  = X + h2 @ Wu2 + bu2 ;  out = LayerNorm(x)*gamma + beta
// Kernel 1 (grid 13 x 1024): blocks 0-11 pack weights to bf16 MFMA-frag order
//   in d_ws; block 12 builds deterministic CSR with a fully parallel counting
//   sort (12x135 chunk counts + shfl prefix scan — no serial section).
// Kernel 2 (grid 256, 1024 thr = 16 waves): whole layer per batch in LDS.

#define NN 81
#define HH 128
#define EE 1620
#define NCH 12
#define CHSZ 135                        // EE / NCH
#define MPAD 96
#define WB_BYTES 196608                 // 6 * 16384 ushorts
#define OFFS_OFF (WB_BYTES)             // int offs[82]
#define CSR_OFF  (WB_BYTES + 82 * 4)    // int csr[1620]
#define WS_NEED  (CSR_OFF + EE * 4)

typedef __attribute__((ext_vector_type(8))) short bf16x8;
typedef __attribute__((ext_vector_type(8))) unsigned short ushort8v;
typedef __attribute__((ext_vector_type(4))) unsigned short ushort4v;
typedef __attribute__((ext_vector_type(4))) float f32x4;

__device__ __forceinline__ unsigned short f2b(float f) {
  union { float f; unsigned u; } v; v.f = f;
  unsigned r = v.u + 0x7fffu + ((v.u >> 16) & 1u);
  return (unsigned short)(r >> 16);
}
__device__ __forceinline__ float b2f(unsigned short h) {
  union { unsigned u; float f; } v; v.u = ((unsigned)h) << 16;
  return v.f;
}

// ---------------- setup kernel: weight pack (blocks 0-11) + CSR (block 12) ----
__global__ __launch_bounds__(1024)
void setup_kernel(const float* __restrict__ Wm1, const float* __restrict__ Wm2,
                  const float* __restrict__ Wu1, const float* __restrict__ Wu2,
                  const int* __restrict__ eidx, char* __restrict__ ws) {
  __shared__ int edg[2 * EE];
  __shared__ int cnt[NCH][NN];
  __shared__ int tot[NN];
  __shared__ int scanS[128];
  __shared__ int wsumS[2];
  __shared__ int offsS[NN + 1];
  __shared__ int csrS[EE];

  if (blockIdx.x < 12) {
    // ---- weight pack: 12*1024 = 12288 threads = 6 mats * 8 nt * 4 ks * 64 ----
    const int gid = blockIdx.x * 1024 + threadIdx.x;
    const int lane = gid & 63;
    const int t = gid >> 6;                 // mat*32 + nt*4 + ks  (0..191)
    const int ks = t & 3, nt = (t >> 2) & 7, mat = t >> 5;
    const float* src;
    if (mat == 0) src = Wm1;
    else if (mat == 1) src = Wm1 + HH * HH;
    else if (mat == 2) src = Wm2;
    else if (mat == 3) src = Wu1;
    else if (mat == 4) src = Wu1 + HH * HH;
    else src = Wu2;
    const int c = nt * 16 + (lane & 15);
    const int k0 = ks * 32 + (lane >> 4) * 8;
    bf16x8 pv;
#pragma unroll
    for (int j = 0; j < 8; ++j) pv[j] = (short)f2b(src[(k0 + j) * HH + c]);
    *(bf16x8*)((unsigned short*)ws + (size_t)mat * 16384 + (((nt * 4 + ks) * 64) + lane) * 8) = pv;
    return;
  }

  // ---- block 12: deterministic CSR, fully parallel ----
  const int tid = threadIdx.x;
  for (int i = tid; i < 2 * EE; i += 1024) edg[i] = eidx[i];
  __syncthreads();
  // chunk counts: thread = ch*NN + t  (972 threads)
  if (tid < NCH * NN) {
    const int t = tid % NN, ch = tid / NN;
    const int e0 = ch * CHSZ, e1 = e0 + CHSZ;
    int c = 0;
    for (int e = e0; e < e1; ++e) c += (edg[EE + e] == t);
    cnt[ch][tid / NN == ch ? t : t] = 0;  // no-op guard (keeps compiler honest)
    cnt[ch][t] = c;
  }
  __syncthreads();
  // per-target totals
  if (tid < NN) {
    int s = 0;
#pragma unroll
    for (int ch = 0; ch < NCH; ++ch) s += cnt[ch][tid];
    tot[tid] = s;
  }
  __syncthreads();
  // parallel exclusive prefix over 81 totals (2-wave shfl scan)
  if (tid < 128) {
    const int l = tid & 63, w = tid >> 6;
    int inc = (tid < NN) ? tot[tid] : 0;
#pragma unroll
    for (int d = 1; d < 64; d <<= 1) {
      int u = __shfl_up(inc, d);
      if (l >= d) inc += u;
    }
    scanS[tid] = inc;
    if (l == 63) wsumS[w] = inc;
  }
  __syncthreads();
  if (tid < 128) {
    const int w = tid >> 6;
    const int inc = scanS[tid] + (w ? wsumS[0] : 0);
    if (tid < NN) offsS[tid] = inc - tot[tid];
    if (tid == NN - 1) offsS[NN] = inc;
  }
  __syncthreads();
  // scatter: thread = ch*NN + t, base = offs[t] + preceding chunk counts
  if (tid < NCH * NN) {
    const int t = tid % NN, ch = tid / NN;
    int pos = offsS[t];
    for (int c2 = 0; c2 < ch; ++c2) pos += cnt[c2][t];
    const int e0 = ch * CHSZ, e1 = e0 + CHSZ;
    for (int e = e0; e < e1; ++e)
      if (edg[EE + e] == t) csrS[pos++] = edg[e];
  }
  __syncthreads();
  int* wofs = (int*)(ws + OFFS_OFF);
  int* wcsr = (int*)(ws + CSR_OFF);
  for (int i = tid; i < NN + 1; i += 1024) wofs[i] = offsS[i];
  for (int i = tid; i < EE; i += 1024) wcsr[i] = csrS[i];
}

// ---------------- MFMA tile GEMM helpers (per wave: 3 M-tiles x 1 N-tile) -----
__device__ __forceinline__ void gemm3x1(const unsigned short* Ab, const unsigned short* Wp,
                                        int lane, int mt0, int nt0, f32x4 acc[3]) {
  bf16x8 Bf[4];
#pragma unroll
  for (int ks = 0; ks < 4; ++ks)
    Bf[ks] = *(const bf16x8*)(Wp + ((nt0 * 4 + ks) * 64 + lane) * 8);
  const int rl = lane & 15;
  const int kb = (lane >> 4) * 16;
  const unsigned swz = (unsigned)((rl & 7) << 4);
#pragma unroll
  for (int ks = 0; ks < 4; ++ks)
#pragma unroll
    for (int mm = 0; mm < 3; ++mm) {
      const int r = (mt0 + mm) * 16 + rl;
      const unsigned byte = (unsigned)(r * 256) + (((unsigned)(ks * 64 + kb)) ^ swz);
      bf16x8 a = *(const bf16x8*)((const char*)Ab + byte);
      acc[mm] = __builtin_amdgcn_mfma_f32_16x16x32_bf16(a, Bf[ks], acc[mm], 0, 0, 0);
    }
}

// dual-B: same A, two packed matrices (saves the A re-read)
__device__ __forceinline__ void gemm3x1x2(const unsigned short* Ab,
                                          const unsigned short* Wp0, const unsigned short* Wp1,
                                          int lane, int mt0, int nt0,
                                          f32x4 acc0[3], f32x4 acc1[3]) {
  bf16x8 B0[4], B1[4];
#pragma unroll
  for (int ks = 0; ks < 4; ++ks) {
    B0[ks] = *(const bf16x8*)(Wp0 + ((nt0 * 4 + ks) * 64 + lane) * 8);
    B1[ks] = *(const bf16x8*)(Wp1 + ((nt0 * 4 + ks) * 64 + lane) * 8);
  }
  const int rl = lane & 15;
  const int kb = (lane >> 4) * 16;
  const unsigned swz = (unsigned)((rl & 7) << 4);
#pragma unroll
  for (int ks = 0; ks < 4; ++ks)
#pragma unroll
    for (int mm = 0; mm < 3; ++mm) {
      const int r = (mt0 + mm) * 16 + rl;
      const unsigned byte = (unsigned)(r * 256) + (((unsigned)(ks * 64 + kb)) ^ swz);
      bf16x8 a = *(const bf16x8*)((const char*)Ab + byte);
      acc0[mm] = __builtin_amdgcn_mfma_f32_16x16x32_bf16(a, B0[ks], acc0[mm], 0, 0, 0);
      acc1[mm] = __builtin_amdgcn_mfma_f32_16x16x32_bf16(a, B1[ks], acc1[mm], 0, 0, 0);
    }
}

__global__ __launch_bounds__(1024, 4)
void mpnn_mfma2_kernel(const float* __restrict__ node,
                       const float* __restrict__ bm1, const float* __restrict__ bm2,
                       const float* __restrict__ bu1, const float* __restrict__ bu2,
                       const float* __restrict__ gamma_, const float* __restrict__ beta_,
                       const char* __restrict__ ws,
                       float* __restrict__ out) {
  __shared__ float X[NN][HH];                 // fp32 for residual + LN
  __shared__ unsigned short Xb[MPAD * HH];    // swizzled bf16
  __shared__ unsigned short bufP[MPAD * HH];  // P -> agg
  __shared__ unsigned short bufQ[MPAD * HH];  // Q -> Hsum -> h2
  __shared__ int   csrL[EE];
  __shared__ int   offsL[NN + 1];
  __shared__ float bias[6][HH];               // bm1,bm2,bu1,bu2,gamma,beta

  const int tid  = threadIdx.x;
  const int lane = tid & 63;
  const int wave = tid >> 6;     // 0..15
  const int b    = blockIdx.x;

  const unsigned short* wpk = (const unsigned short*)ws;
  const int* wofs = (const int*)(ws + OFFS_OFF);
  const int* wcsr = (const int*)(ws + CSR_OFF);

  // ---- stage: X fp32 + Xb bf16 (swizzled), csr/offs, biases, zero-pad ----
  {
    const float4* nf4 = (const float4*)(node + (size_t)b * NN * HH);
    for (int i = tid; i < NN * HH / 4; i += 1024) {
      float4 v = nf4[i];
      const int f = i * 4, r = f >> 7, c = f & 127;
      *(float4*)&X[r][c] = v;
      ushort4v pv = { f2b(v.x), f2b(v.y), f2b(v.z), f2b(v.w) };
      const unsigned byte = ((unsigned)(r * 256 + c * 2)) ^ ((unsigned)((r & 7) << 4));
      *(ushort4v*)((char*)Xb + byte) = pv;
    }
    if (tid < (MPAD - NN) * 16) {   // zero rows 81..95
      const int r = NN + tid / 16, m = tid % 16;
      const unsigned byte = ((unsigned)(r * 256 + m * 16)) ^ ((unsigned)((r & 7) << 4));
      ushort8v z = {0,0,0,0,0,0,0,0};
      *(ushort8v*)((char*)Xb + byte) = z;
    }
    for (int i = tid; i < EE; i += 1024) csrL[i] = wcsr[i];
    if (tid < NN + 1) offsL[tid] = wofs[tid];
    if (tid < HH) {
      bias[0][tid] = bm1[tid]; bias[1][tid] = bm2[tid];
      bias[2][tid] = bu1[tid]; bias[3][tid] = bu2[tid];
      bias[4][tid] = gamma_[tid]; bias[5][tid] = beta_[tid];
    }
  }
  __syncthreads();

  // ---- wave tile map: 16 waves = 8 N-tiles x 2 M-halves (3 M-tiles each) ----
  const int nt0 = wave & 7;
  const int mt0 = 3 * (wave >> 3);
  const int erow = (lane >> 4) * 4;
  const int ecol = lane & 15;

  // ---- GEMM A: P = Xb@Wm1t -> bufP ; Q = Xb@Wm1b -> bufQ ;
  //      U = Xb@Wu1t kept in registers until GEMM C ----
  f32x4 accU[3];
  {
    f32x4 accP[3], accQ[3];
#pragma unroll
    for (int mm = 0; mm < 3; ++mm) { accP[mm] = (f32x4)0.f; accQ[mm] = (f32x4)0.f; accU[mm] = (f32x4)0.f; }
    gemm3x1x2(Xb, wpk, wpk + 16384, lane, mt0, nt0, accP, accQ);
    gemm3x1(Xb, wpk + 3 * 16384, lane, mt0, nt0, accU);
#pragma unroll
    for (int mm = 0; mm < 3; ++mm)
#pragma unroll
      for (int rg = 0; rg < 4; ++rg) {
        const int R = (mt0 + mm) * 16 + erow + rg;
        const int C = nt0 * 16 + ecol;
        const unsigned byte = ((unsigned)(R * 256 + C * 2)) ^ ((unsigned)((R & 7) << 4));
        const bool ok = (R < NN);
        *(unsigned short*)((char*)bufP + byte) = ok ? f2b(accP[mm][rg]) : (unsigned short)0;
        *(unsigned short*)((char*)bufQ + byte) = ok ? f2b(accQ[mm][rg]) : (unsigned short)0;
      }
  }
  __syncthreads();

  // ---- edge aggregation: Hsum[t] = sum relu(P[s] + Q[t] + bm1) -> bufQ ----
  {
    const float bm1a = bias[0][2 * lane];
    const float bm1b = bias[0][2 * lane + 1];
    for (int t = wave; t < NN; t += 16) {
      const unsigned qbyte = ((unsigned)(t * 256 + lane * 4)) ^ ((unsigned)((t & 7) << 4));
      const unsigned pq = *(const unsigned*)((const char*)bufQ + qbyte);
      const float q0 = b2f((unsigned short)(pq & 0xffff)) + bm1a;
      const float q1 = b2f((unsigned short)(pq >> 16))    + bm1b;
      float h0 = 0.f, h1 = 0.f;
      const int o0 = offsL[t], o1 = offsL[t + 1];
      for (int e = o0; e < o1; ++e) {
        const int s = csrL[e];
        const unsigned pb = ((unsigned)(s * 256 + lane * 4)) ^ ((unsigned)((s & 7) << 4));
        const unsigned pp = *(const unsigned*)((const char*)bufP + pb);
        h0 += fmaxf(b2f((unsigned short)(pp & 0xffff)) + q0, 0.f);
        h1 += fmaxf(b2f((unsigned short)(pp >> 16))    + q1, 0.f);
      }
      const unsigned hv = (unsigned)f2b(h0) | ((unsigned)f2b(h1) << 16);
      *(unsigned*)((char*)bufQ + qbyte) = hv;
    }
  }
  __syncthreads();

  // ---- GEMM B: agg = (Hsum@Wm2 + deg*bm2)/max(deg,1) -> bufP ----
  {
    f32x4 acc[3];
#pragma unroll
    for (int mm = 0; mm < 3; ++mm) acc[mm] = (f32x4)0.f;
    gemm3x1(bufQ, wpk + 2 * 16384, lane, mt0, nt0, acc);
#pragma unroll
    for (int mm = 0; mm < 3; ++mm)
#pragma unroll
      for (int rg = 0; rg < 4; ++rg) {
        const int R = (mt0 + mm) * 16 + erow + rg;
        const int C = nt0 * 16 + ecol;
        float v = 0.f;
        if (R < NN) {
          const float dg = (float)(offsL[R + 1] - offsL[R]);
          v = (acc[mm][rg] + dg * bias[1][C]) * (1.f / fmaxf(dg, 1.f));
        }
        const unsigned byte = ((unsigned)(R * 256 + C * 2)) ^ ((unsigned)((R & 7) << 4));
        *(unsigned short*)((char*)bufP + byte) = f2b(v);
      }
  }
  __syncthreads();

  // ---- GEMM C: h2 = relu(U + agg@Wu1b + bu1) -> bufQ ----
  {
    gemm3x1(bufP, wpk + 4 * 16384, lane, mt0, nt0, accU);
#pragma unroll
    for (int mm = 0; mm < 3; ++mm)
#pragma unroll
      for (int rg = 0; rg < 4; ++rg) {
        const int R = (mt0 + mm) * 16 + erow + rg;
        const int C = nt0 * 16 + ecol;
        const float v = (R < NN) ? fmaxf(accU[mm][rg] + bias[2][C], 0.f) : 0.f;
        const unsigned byte = ((unsigned)(R * 256 + C * 2)) ^ ((unsigned)((R & 7) << 4));
        *(unsigned short*)((char*)bufQ + byte) = f2b(v);
      }
  }
  __syncthreads();

  // ---- GEMM D: x = X + h2@Wu2 + bu2 (in place into X fp32) ----
  {
    f32x4 acc[3];
#pragma unroll
    for (int mm = 0; mm < 3; ++mm) acc[mm] = (f32x4)0.f;
    gemm3x1(bufQ, wpk + 5 * 16384, lane, mt0, nt0, acc);
#pragma unroll
    for (int mm = 0; mm < 3; ++mm)
#pragma unroll
      for (int rg = 0; rg < 4; ++rg) {
        const int R = (mt0 + mm) * 16 + erow + rg;
        const int C = nt0 * 16 + ecol;
        if (R < NN) X[R][C] += acc[mm][rg] + bias[3][C];
      }
  }
  __syncthreads();

  // ---- LayerNorm per row + store ----
  for (int r = wave; r < NN; r += 16) {
    const float x0 = X[r][lane], x1 = X[r][lane + 64];
    float s = x0 + x1;
#pragma unroll
    for (int off = 32; off; off >>= 1) s += __shfl_xor(s, off);
    const float mu = s * (1.f / 128.f);
    const float d0 = x0 - mu, d1 = x1 - mu;
    float v = d0 * d0 + d1 * d1;
#pragma unroll
    for (int off = 32; off; off >>= 1) v += __shfl_xor(v, off);
    const float rstd = rsqrtf(v * (1.f / 128.f) + 1e-5f);
    const size_t o = ((size_t)b * NN + r) * HH;
    out[o + lane]      = d0 * rstd * bias[4][lane]      + bias[5][lane];
    out[o + lane + 64] = d1 * rstd * bias[4][lane + 64] + bias[5][lane + 64];
  }
}

// ================= fp32 fallback (known-good, used only if ws too small) =====
__device__ __forceinline__ void gemm_acc_f32(const float (*A)[HH], const float* __restrict__ Wg,
                                             int c, int row0, int nr, float (&acc)[41]) {
  float w[8];
#pragma unroll
  for (int j = 0; j < 8; ++j) w[j] = Wg[j * HH + c];
  for (int k0 = 0; k0 < HH; k0 += 8) {
    float wn[8];
    if (k0 + 8 < HH) {
#pragma unroll
      for (int j = 0; j < 8; ++j) wn[j] = Wg[(k0 + 8 + j) * HH + c];
    }
#pragma unroll
    for (int i = 0; i < 41; ++i) {
      if (i < nr) {
        const float4 a0 = *(const float4*)&A[row0 + i][k0];
        const float4 a1 = *(const float4*)&A[row0 + i][k0 + 4];
        acc[i] += a0.x * w[0] + a0.y * w[1] + a0.z * w[2] + a0.w * w[3]
                + a1.x * w[4] + a1.y * w[5] + a1.z * w[6] + a1.w * w[7];
      }
    }
#pragma unroll
    for (int j = 0; j < 8; ++j) w[j] = wn[j];
  }
}

__global__ __launch_bounds__(256, 1)
void mpnn_fused_kernel(const float* __restrict__ node, const int* __restrict__ eidx,
                       const float* __restrict__ Wm1, const float* __restrict__ bm1,
                       const float* __restrict__ Wm2, const float* __restrict__ bm2,
                       const float* __restrict__ Wu1, const float* __restrict__ bu1,
                       const float* __restrict__ Wu2, const float* __restrict__ bu2,
                       const float* __restrict__ gamma_, const float* __restrict__ beta_,
                       float* __restrict__ out) {
  __shared__ float X[NN][HH];
  __shared__ float Pb[NN][HH];
  __shared__ float Qb[NN][HH];
  __shared__ int   edg[2 * EE];
  __shared__ int   csr[EE];
  __shared__ int   offs[NN + 1];
  __shared__ int   cnt3[3][NN];
  __shared__ int   base3[3][NN];
  __shared__ float biases[6][HH];

  const int tid  = threadIdx.x;
  const int lane = tid & 63;
  const int wave = tid >> 6;
  const int b    = blockIdx.x;

  {
    const float4* nf4 = (const float4*)(node + (size_t)b * NN * HH);
    float4* X4 = (float4*)&X[0][0];
    for (int i = tid; i < NN * HH / 4; i += 256) X4[i] = nf4[i];
    for (int i = tid; i < 2 * EE; i += 256) edg[i] = eidx[i];
    if (tid < HH) {
      biases[0][tid] = bm1[tid]; biases[1][tid] = bm2[tid];
      biases[2][tid] = bu1[tid]; biases[3][tid] = bu2[tid];
      biases[4][tid] = gamma_[tid]; biases[5][tid] = beta_[tid];
    }
  }
  __syncthreads();
  if (tid < 3 * NN) {
    const int t = tid % NN, ch = tid / NN;
    const int e0 = ch * 540, e1 = e0 + 540;
    int cnt = 0;
    for (int e = e0; e < e1; ++e) cnt += (edg[EE + e] == t);
    cnt3[ch][t] = cnt;
  }
  __syncthreads();
  if (tid == 0) {
    int run = 0;
    for (int t = 0; t < NN; ++t) {
      offs[t] = run;
      base3[0][t] = run;
      base3[1][t] = base3[0][t] + cnt3[0][t];
      base3[2][t] = base3[1][t] + cnt3[1][t];
      run = base3[2][t] + cnt3[2][t];
    }
    offs[NN] = run;
  }
  __syncthreads();
  if (tid < 3 * NN) {
    const int t = tid % NN, ch = tid / NN;
    const int e0 = ch * 540, e1 = e0 + 540;
    int pos = base3[ch][t];
    for (int e = e0; e < e1; ++e)
      if (edg[EE + e] == t) csr[pos++] = edg[e];
  }
  __syncthreads();

  const int c    = ((wave & 1) << 6) | lane;
  const int row0 = (wave >> 1) ? 41 : 0;
  const int nr   = (wave >> 1) ? 40 : 41;

  {
    float acc[41];
#pragma unroll
    for (int i = 0; i < 41; ++i) acc[i] = 0.f;
    gemm_acc_f32(X, Wm1, c, row0, nr, acc);
#pragma unroll
    for (int i = 0; i < 41; ++i) if (i < nr) Pb[row0 + i][c] = acc[i];
  }
  {
    float acc[41];
#pragma unroll
    for (int i = 0; i < 41; ++i) acc[i] = 0.f;
    gemm_acc_f32(X, Wm1 + HH * HH, c, row0, nr, acc);
#pragma unroll
    for (int i = 0; i < 41; ++i) if (i < nr) Qb[row0 + i][c] = acc[i];
  }
  __syncthreads();

  for (int t = wave; t < NN; t += 4) {
    const int o0 = offs[t], o1 = offs[t + 1];
    const float q0 = Qb[t][lane]      + biases[0][lane];
    const float q1 = Qb[t][lane + 64] + biases[0][lane + 64];
    float h0 = 0.f, h1 = 0.f;
    for (int e = o0; e < o1; ++e) {
      const int s = csr[e];
      h0 += fmaxf(Pb[s][lane]      + q0, 0.f);
      h1 += fmaxf(Pb[s][lane + 64] + q1, 0.f);
    }
    Qb[t][lane]      = h0;
    Qb[t][lane + 64] = h1;
  }
  __syncthreads();

  {
    float acc[41];
#pragma unroll
    for (int i = 0; i < 41; ++i) acc[i] = 0.f;
    gemm_acc_f32(Qb, Wm2, c, row0, nr, acc);
#pragma unroll
    for (int i = 0; i < 41; ++i) if (i < nr) {
      const int r = row0 + i;
      const float d = (float)(offs[r + 1] - offs[r]);
      Pb[r][c] = (acc[i] + d * biases[1][c]) * (1.f / fmaxf(d, 1.f));
    }
  }
  __syncthreads();

  {
    float acc[41];
#pragma unroll
    for (int i = 0; i < 41; ++i) acc[i] = 0.f;
    gemm_acc_f32(X,  Wu1,           c, row0, nr, acc);
    gemm_acc_f32(Pb, Wu1 + HH * HH, c, row0, nr, acc);
#pragma unroll
    for (int i = 0; i < 41; ++i) if (i < nr)
      Qb[row0 + i][c] = fmaxf(acc[i] + biases[2][c], 0.f);
  }
  __syncthreads();

  {
    float acc[41];
#pragma unroll
    for (int i = 0; i < 41; ++i) acc[i] = 0.f;
    gemm_acc_f32(Qb, Wu2, c, row0, nr, acc);
#pragma unroll
    for (int i = 0; i < 41; ++i) if (i < nr) {
      const int r = row0 + i;
      X[r][c] = X[r][c] + acc[i] + biases[3][c];
    }
  }
  __syncthreads();

  for (int r = wave; r < NN; r += 4) {
    const float x0 = X[r][lane], x1 = X[r][lane + 64];
    float s = x0 + x1;
#pragma unroll
    for (int off = 32; off; off >>= 1) s += __shfl_xor(s, off);
    const float mu = s * (1.f / 128.f);
    const float d0 = x0 - mu, d1 = x1 - mu;
    float v = d0 * d0 + d1 * d1;
#pragma unroll
    for (int off = 32; off; off >>= 1) v += __shfl_xor(v, off);
    const float rstd = rsqrtf(v * (1.f / 128.f) + 1e-5f);
    const size_t o = ((size_t)b * NN + r) * HH;
    out[o + lane]      = d0 * rstd * biases[4][lane]      + biases[5][lane];
    out[o + lane + 64] = d1 * rstd * biases[4][lane + 64] + biases[5][lane + 64];
  }
}

extern "C" void kernel_launch(void* const* d_in, const int* in_sizes, int n_in,
                              void* d_out, int out_size, void* d_ws, size_t ws_size,
                              hipStream_t stream) {
  (void)in_sizes; (void)n_in; (void)out_size;
  const float* node  = (const float*)d_in[0];
  const int*   eidx  = (const int*)  d_in[1];
  const float* Wm1   = (const float*)d_in[2];
  const float* bm1   = (const float*)d_in[3];
  const float* Wm2   = (const float*)d_in[4];
  const float* bm2   = (const float*)d_in[5];
  const float* Wu1   = (const float*)d_in[6];
  const float* bu1   = (const float*)d_in[7];
  const float* Wu2   = (const float*)d_in[8];
  const float* bu2   = (const float*)d_in[9];
  const float* gamma_= (const float*)d_in[10];
  const float* beta_ = (const float*)d_in[11];
  float* outp = (float*)d_out;

  if (ws_size >= (size_t)WS_NEED) {
    char* ws = (char*)d_ws;
    hipLaunchKernelGGL(setup_kernel, dim3(13), dim3(1024), 0, stream,
                       Wm1, Wm2, Wu1, Wu2, eidx, ws);
    hipLaunchKernelGGL(mpnn_mfma2_kernel, dim3(256), dim3(1024), 0, stream,
                       node, bm1, bm2, bu1, bu2, gamma_, beta_, ws, outp);
  } else {
    hipLaunchKernelGGL(mpnn_fused_kernel, dim3(256), dim3(256), 0, stream,
                       node, eidx, Wm1, bm1, Wm2, bm2, Wu1, bu1, Wu2, bu2,
                       gamma_, beta_, outp);
  }
}

// Round 5
// 45.504 us; speedup vs baseline: 5.1773x; 1.0320x over previous
//
#include <hip/hip_runtime.h>

// Fused MPNN layer, B=256, N=81, H=128, E=1620 — MFMA bf16.
//   P = X @ Wm1[:H],  Q = X @ Wm1[H:]
//   Hsum[t] = sum_{e: tgt=t} relu(P[src_e] + Q[t] + bm1)
//   Folded:  agg@Wu1b = (Hsum@Wc)*inv_deg + 1[deg>0]*bc,  Wc=Wm2@Wu1b, bc=bm2@Wu1b
//   h2 = relu(X@Wu1t + (Hsum@Wc)*inv + s*bc + bu1)
//   x  = X + h2 @ Wu2 + bu2 ;  out = LayerNorm(x)*gamma + beta
// Setup kernel (grid 13 x 1024): blocks 0-7 pack {Wm1t,Wm1b,Wu1t,Wu2} to bf16
//   MFMA-frag order; block 8 builds deterministic CSR (parallel counting sort);
//   blocks 9-12 compute Wc = Wm2@Wu1b (fp32 in LDS) + pack, block 9 also bc.
// Main kernel (grid 256, 1024 thr = 16 waves): whole layer per batch in LDS.

#define NN 81
#define HH 128
#define EE 1620
#define NCH 12
#define CHSZ 135                        // EE / NCH
#define MPAD 96
#define WB_BYTES 196608                 // 6 * 16384 ushorts (slot4 unused)
#define OFFS_OFF (WB_BYTES)             // int offs[82]
#define CSR_OFF  (OFFS_OFF + 82 * 4)    // int csr[1620]
#define BC_OFF   (CSR_OFF + EE * 4)     // float bc[128]
#define WS_NEED  (BC_OFF + HH * 4)

typedef __attribute__((ext_vector_type(8))) short bf16x8;
typedef __attribute__((ext_vector_type(8))) unsigned short ushort8v;
typedef __attribute__((ext_vector_type(4))) unsigned short ushort4v;
typedef __attribute__((ext_vector_type(4))) float f32x4;

__device__ __forceinline__ unsigned short f2b(float f) {
  union { float f; unsigned u; } v; v.f = f;
  unsigned r = v.u + 0x7fffu + ((v.u >> 16) & 1u);
  return (unsigned short)(r >> 16);
}
__device__ __forceinline__ float b2f(unsigned short h) {
  union { unsigned u; float f; } v; v.u = ((unsigned)h) << 16;
  return v.f;
}
__device__ __forceinline__ unsigned swzu(int r, int laneb) {
  return ((unsigned)(r * 256 + laneb)) ^ ((unsigned)((r & 7) << 4));
}

// ---------------- setup kernel ------------------------------------------------
__global__ __launch_bounds__(1024)
void setup_kernel(const float* __restrict__ Wm1, const float* __restrict__ Wm2,
                  const float* __restrict__ Wu1, const float* __restrict__ Wu2,
                  const float* __restrict__ bm2, const int* __restrict__ eidx,
                  char* __restrict__ ws) {
  __shared__ __align__(16) char arena[81920];
  const int tid = threadIdx.x;

  if (blockIdx.x < 8) {
    // ---- pack 4 source mats: 8*1024 threads = 4 mats * 8 nt * 4 ks * 64 ----
    const int gid = blockIdx.x * 1024 + tid;
    const int lane = gid & 63;
    const int t = gid >> 6;                 // mat*32 + nt*4 + ks  (0..127)
    const int ks = t & 3, nt = (t >> 2) & 7, mat = t >> 5;
    const float* src;
    int slot;
    if (mat == 0)      { src = Wm1;           slot = 0; }
    else if (mat == 1) { src = Wm1 + HH * HH; slot = 1; }
    else if (mat == 2) { src = Wu1;           slot = 3; }
    else               { src = Wu2;           slot = 5; }
    const int c = nt * 16 + (lane & 15);
    const int k0 = ks * 32 + (lane >> 4) * 8;
    bf16x8 pv;
#pragma unroll
    for (int j = 0; j < 8; ++j) pv[j] = (short)f2b(src[(k0 + j) * HH + c]);
    *(bf16x8*)((unsigned short*)ws + (size_t)slot * 16384 + (((nt * 4 + ks) * 64) + lane) * 8) = pv;
    return;
  }

  if (blockIdx.x == 8) {
    // ---- deterministic CSR, fully parallel ----
    int* edg   = (int*)arena;           // 3240
    int* cnt   = edg + 2 * EE;          // NCH*NN
    int* tot   = cnt + NCH * NN;        // NN
    int* scanS = tot + NN;              // 128
    int* wsumS = scanS + 128;           // 2
    int* offsS = wsumS + 2;             // NN+1
    int* csrS  = offsS + NN + 1;        // EE
    for (int i = tid; i < 2 * EE; i += 1024) edg[i] = eidx[i];
    __syncthreads();
    if (tid < NCH * NN) {
      const int t = tid % NN, ch = tid / NN;
      const int e0 = ch * CHSZ, e1 = e0 + CHSZ;
      int c = 0;
      for (int e = e0; e < e1; ++e) c += (edg[EE + e] == t);
      cnt[ch * NN + t] = c;
    }
    __syncthreads();
    if (tid < NN) {
      int s = 0;
#pragma unroll
      for (int ch = 0; ch < NCH; ++ch) s += cnt[ch * NN + tid];
      tot[tid] = s;
    }
    __syncthreads();
    if (tid < 128) {
      const int l = tid & 63, w = tid >> 6;
      int inc = (tid < NN) ? tot[tid] : 0;
#pragma unroll
      for (int d = 1; d < 64; d <<= 1) {
        int u = __shfl_up(inc, d);
        if (l >= d) inc += u;
      }
      scanS[tid] = inc;
      if (l == 63) wsumS[w] = inc;
    }
    __syncthreads();
    if (tid < 128) {
      const int w = tid >> 6;
      const int inc = scanS[tid] + (w ? wsumS[0] : 0);
      if (tid < NN) offsS[tid] = inc - tot[tid];
      if (tid == NN - 1) offsS[NN] = inc;
    }
    __syncthreads();
    if (tid < NCH * NN) {
      const int t = tid % NN, ch = tid / NN;
      int pos = offsS[t];
      for (int c2 = 0; c2 < ch; ++c2) pos += cnt[c2 * NN + t];
      const int e0 = ch * CHSZ, e1 = e0 + CHSZ;
      for (int e = e0; e < e1; ++e)
        if (edg[EE + e] == t) csrS[pos++] = edg[e];
    }
    __syncthreads();
    int* wofs = (int*)(ws + OFFS_OFF);
    int* wcsr = (int*)(ws + CSR_OFF);
    for (int i = tid; i < NN + 1; i += 1024) wofs[i] = offsS[i];
    for (int i = tid; i < EE; i += 1024) wcsr[i] = csrS[i];
    return;
  }

  // ---- blocks 9-12: Wc = Wm2 @ Wu1b, rows [32*bs, 32*bs+32); pack slot 2 ----
  {
    const int bs = blockIdx.x - 9;      // = ks slice
    float* WuL = (float*)arena;         // [128][128]
    float* WmL = WuL + HH * HH;         // [32][128]
    const float* Wu1b = Wu1 + HH * HH;
    float4* WuL4 = (float4*)WuL;
    const float4* src4 = (const float4*)Wu1b;
    for (int i = tid; i < HH * HH / 4; i += 1024) WuL4[i] = src4[i];
    const float4* wm4 = (const float4*)(Wm2 + bs * 32 * HH);
    float4* WmL4 = (float4*)WmL;
    if (tid < 32 * HH / 4) WmL4[tid] = wm4[tid];
    __syncthreads();
    const int kk = tid >> 5;            // 0..31 local row
    const int k  = bs * 32 + kk;
    const int cg = tid & 31;            // float4 col group
    f32x4 acc = (f32x4)0.f;
    for (int j = 0; j < HH; ++j) {
      const float a = WmL[kk * HH + j];
      const float4 w = WuL4[j * 32 + cg];
      acc[0] += a * w.x; acc[1] += a * w.y; acc[2] += a * w.z; acc[3] += a * w.w;
    }
    unsigned short* dst = (unsigned short*)ws;
#pragma unroll
    for (int q = 0; q < 4; ++q) {
      const int c = cg * 4 + q;
      const int nt = c >> 4;
      const int l = (((k & 31) >> 3) << 4) | (c & 15);
      dst[(size_t)2 * 16384 + (((nt * 4 + bs) * 64) + l) * 8 + (k & 7)] = f2b(acc[q]);
    }
    if (bs == 0 && tid < HH) {
      float s = 0.f;
      for (int j = 0; j < HH; ++j) s += bm2[j] * WuL[j * HH + tid];
      ((float*)(ws + BC_OFF))[tid] = s;
    }
  }
}

// ---------------- MFMA tile GEMM helpers (per wave: 3 M-tiles x 1 N-tile) -----
__device__ __forceinline__ void gemm3x1(const unsigned short* Ab, const unsigned short* Wp,
                                        int lane, int mt0, int nt0, f32x4 acc[3]) {
  bf16x8 Bf[4];
#pragma unroll
  for (int ks = 0; ks < 4; ++ks)
    Bf[ks] = *(const bf16x8*)(Wp + ((nt0 * 4 + ks) * 64 + lane) * 8);
  const int rl = lane & 15;
  const int kb = (lane >> 4) * 16;
  const unsigned swz = (unsigned)((rl & 7) << 4);
#pragma unroll
  for (int ks = 0; ks < 4; ++ks)
#pragma unroll
    for (int mm = 0; mm < 3; ++mm) {
      const int r = (mt0 + mm) * 16 + rl;
      const unsigned byte = (unsigned)(r * 256) + (((unsigned)(ks * 64 + kb)) ^ swz);
      bf16x8 a = *(const bf16x8*)((const char*)Ab + byte);
      acc[mm] = __builtin_amdgcn_mfma_f32_16x16x32_bf16(a, Bf[ks], acc[mm], 0, 0, 0);
    }
}

// dual-B, same A
__device__ __forceinline__ void gemm3x1x2(const unsigned short* Ab,
                                          const unsigned short* Wp0, const unsigned short* Wp1,
                                          int lane, int mt0, int nt0,
                                          f32x4 acc0[3], f32x4 acc1[3]) {
  bf16x8 B0[4], B1[4];
#pragma unroll
  for (int ks = 0; ks < 4; ++ks) {
    B0[ks] = *(const bf16x8*)(Wp0 + ((nt0 * 4 + ks) * 64 + lane) * 8);
    B1[ks] = *(const bf16x8*)(Wp1 + ((nt0 * 4 + ks) * 64 + lane) * 8);
  }
  const int rl = lane & 15;
  const int kb = (lane >> 4) * 16;
  const unsigned swz = (unsigned)((rl & 7) << 4);
#pragma unroll
  for (int ks = 0; ks < 4; ++ks)
#pragma unroll
    for (int mm = 0; mm < 3; ++mm) {
      const int r = (mt0 + mm) * 16 + rl;
      const unsigned byte = (unsigned)(r * 256) + (((unsigned)(ks * 64 + kb)) ^ swz);
      bf16x8 a = *(const bf16x8*)((const char*)Ab + byte);
      acc0[mm] = __builtin_amdgcn_mfma_f32_16x16x32_bf16(a, B0[ks], acc0[mm], 0, 0, 0);
      acc1[mm] = __builtin_amdgcn_mfma_f32_16x16x32_bf16(a, B1[ks], acc1[mm], 0, 0, 0);
    }
}

// dual-A, two B mats (T = Hsum@Wc, U = Xb@Wu1t share the K-loop)
__device__ __forceinline__ void gemm3x1_2A(const unsigned short* A0, const unsigned short* A1,
                                           const unsigned short* Wp0, const unsigned short* Wp1,
                                           int lane, int mt0, int nt0,
                                           f32x4 acc0[3], f32x4 acc1[3]) {
  bf16x8 B0[4], B1[4];
#pragma unroll
  for (int ks = 0; ks < 4; ++ks) {
    B0[ks] = *(const bf16x8*)(Wp0 + ((nt0 * 4 + ks) * 64 + lane) * 8);
    B1[ks] = *(const bf16x8*)(Wp1 + ((nt0 * 4 + ks) * 64 + lane) * 8);
  }
  const int rl = lane & 15;
  const int kb = (lane >> 4) * 16;
  const unsigned swz = (unsigned)((rl & 7) << 4);
#pragma unroll
  for (int ks = 0; ks < 4; ++ks)
#pragma unroll
    for (int mm = 0; mm < 3; ++mm) {
      const int r = (mt0 + mm) * 16 + rl;
      const unsigned byte = (unsigned)(r * 256) + (((unsigned)(ks * 64 + kb)) ^ swz);
      bf16x8 a0 = *(const bf16x8*)((const char*)A0 + byte);
      acc0[mm] = __builtin_amdgcn_mfma_f32_16x16x32_bf16(a0, B0[ks], acc0[mm], 0, 0, 0);
      bf16x8 a1 = *(const bf16x8*)((const char*)A1 + byte);
      acc1[mm] = __builtin_amdgcn_mfma_f32_16x16x32_bf16(a1, B1[ks], acc1[mm], 0, 0, 0);
    }
}

__global__ __launch_bounds__(1024, 4)
void mpnn_mfma3_kernel(const float* __restrict__ node,
                       const float* __restrict__ bm1,
                       const float* __restrict__ bu1, const float* __restrict__ bu2,
                       const float* __restrict__ gamma_, const float* __restrict__ beta_,
                       const char* __restrict__ ws,
                       float* __restrict__ out) {
  __shared__ float X[NN][HH];                 // fp32 for residual + LN
  __shared__ unsigned short Xb[MPAD * HH];    // swizzled bf16
  __shared__ unsigned short bufP[MPAD * HH];  // P -> h2
  __shared__ unsigned short bufQ[MPAD * HH];  // Q -> Hsum
  __shared__ int   csrL[EE];
  __shared__ int   offsL[NN + 1];
  __shared__ float bias[6][HH];               // bm1,bc,bu1,bu2,gamma,beta

  const int tid  = threadIdx.x;
  const int lane = tid & 63;
  const int wave = tid >> 6;     // 0..15
  const int b    = blockIdx.x;

  const unsigned short* wpk = (const unsigned short*)ws;
  const int* wofs = (const int*)(ws + OFFS_OFF);
  const int* wcsr = (const int*)(ws + CSR_OFF);
  const float* wbc = (const float*)(ws + BC_OFF);

  // ---- stage ----
  {
    const float4* nf4 = (const float4*)(node + (size_t)b * NN * HH);
    for (int i = tid; i < NN * HH / 4; i += 1024) {
      float4 v = nf4[i];
      const int f = i * 4, r = f >> 7, c = f & 127;
      *(float4*)&X[r][c] = v;
      ushort4v pv = { f2b(v.x), f2b(v.y), f2b(v.z), f2b(v.w) };
      *(ushort4v*)((char*)Xb + swzu(r, c * 2)) = pv;
    }
    if (tid < (MPAD - NN) * 16) {   // zero pad rows 81..95
      const int r = NN + tid / 16, m = tid % 16;
      ushort8v z = {0,0,0,0,0,0,0,0};
      *(ushort8v*)((char*)Xb + swzu(r, m * 16)) = z;
    }
    for (int i = tid; i < EE; i += 1024) csrL[i] = wcsr[i];
    if (tid < NN + 1) offsL[tid] = wofs[tid];
    if (tid < HH) {
      bias[0][tid] = bm1[tid];  bias[1][tid] = wbc[tid];
      bias[2][tid] = bu1[tid];  bias[3][tid] = bu2[tid];
      bias[4][tid] = gamma_[tid]; bias[5][tid] = beta_[tid];
    }
  }
  __syncthreads();

  // ---- wave tile map: 16 waves = 8 N-tiles x 2 M-halves (3 M-tiles each) ----
  const int nt0 = wave & 7;
  const int mt0 = 3 * (wave >> 3);
  const int erow = (lane >> 4) * 4;
  const int ecol = lane & 15;

  // ---- GEMM A: P = Xb@Wm1t -> bufP ; Q = Xb@Wm1b -> bufQ ----
  {
    f32x4 accP[3], accQ[3];
#pragma unroll
    for (int mm = 0; mm < 3; ++mm) { accP[mm] = (f32x4)0.f; accQ[mm] = (f32x4)0.f; }
    gemm3x1x2(Xb, wpk, wpk + 16384, lane, mt0, nt0, accP, accQ);
#pragma unroll
    for (int mm = 0; mm < 3; ++mm)
#pragma unroll
      for (int rg = 0; rg < 4; ++rg) {
        const int R = (mt0 + mm) * 16 + erow + rg;
        const int C = nt0 * 16 + ecol;
        const unsigned byte = swzu(R, C * 2);
        const bool ok = (R < NN);
        *(unsigned short*)((char*)bufP + byte) = ok ? f2b(accP[mm][rg]) : (unsigned short)0;
        *(unsigned short*)((char*)bufQ + byte) = ok ? f2b(accQ[mm][rg]) : (unsigned short)0;
      }
  }
  __syncthreads();

  // ---- edge aggregation (x4 unrolled): Hsum[t] = sum relu(P[s]+Q[t]+bm1) -> bufQ
  {
    const float bm1a = bias[0][2 * lane];
    const float bm1b = bias[0][2 * lane + 1];
    const int lb = lane * 4;
    for (int t = wave; t < NN; t += 16) {
      const unsigned qbyte = swzu(t, lb);
      const unsigned pq = *(const unsigned*)((const char*)bufQ + qbyte);
      const float q0 = b2f((unsigned short)(pq & 0xffff)) + bm1a;
      const float q1 = b2f((unsigned short)(pq >> 16))    + bm1b;
      float h0 = 0.f, h1 = 0.f, g0 = 0.f, g1 = 0.f;
      int e = offsL[t];
      const int o1 = offsL[t + 1];
      for (; e + 4 <= o1; e += 4) {
        const int s0 = csrL[e], s1 = csrL[e + 1], s2 = csrL[e + 2], s3 = csrL[e + 3];
        const unsigned p0 = *(const unsigned*)((const char*)bufP + swzu(s0, lb));
        const unsigned p1 = *(const unsigned*)((const char*)bufP + swzu(s1, lb));
        const unsigned p2 = *(const unsigned*)((const char*)bufP + swzu(s2, lb));
        const unsigned p3 = *(const unsigned*)((const char*)bufP + swzu(s3, lb));
        h0 += fmaxf(b2f((unsigned short)(p0 & 0xffff)) + q0, 0.f);
        h1 += fmaxf(b2f((unsigned short)(p0 >> 16))    + q1, 0.f);
        g0 += fmaxf(b2f((unsigned short)(p1 & 0xffff)) + q0, 0.f);
        g1 += fmaxf(b2f((unsigned short)(p1 >> 16))    + q1, 0.f);
        h0 += fmaxf(b2f((unsigned short)(p2 & 0xffff)) + q0, 0.f);
        h1 += fmaxf(b2f((unsigned short)(p2 >> 16))    + q1, 0.f);
        g0 += fmaxf(b2f((unsigned short)(p3 & 0xffff)) + q0, 0.f);
        g1 += fmaxf(b2f((unsigned short)(p3 >> 16))    + q1, 0.f);
      }
      for (; e < o1; ++e) {
        const int s = csrL[e];
        const unsigned pp = *(const unsigned*)((const char*)bufP + swzu(s, lb));
        h0 += fmaxf(b2f((unsigned short)(pp & 0xffff)) + q0, 0.f);
        h1 += fmaxf(b2f((unsigned short)(pp >> 16))    + q1, 0.f);
      }
      h0 += g0; h1 += g1;
      const unsigned hv = (unsigned)f2b(h0) | ((unsigned)f2b(h1) << 16);
      *(unsigned*)((char*)bufQ + qbyte) = hv;
    }
  }
  __syncthreads();

  // ---- GEMM BC: T = Hsum@Wc ; U = Xb@Wu1t ;
  //      h2 = relu(U + T*inv_deg + s*bc + bu1) -> bufP ----
  {
    f32x4 accT[3], accU[3];
#pragma unroll
    for (int mm = 0; mm < 3; ++mm) { accT[mm] = (f32x4)0.f; accU[mm] = (f32x4)0.f; }
    gemm3x1_2A(bufQ, Xb, wpk + 2 * 16384, wpk + 3 * 16384, lane, mt0, nt0, accT, accU);
#pragma unroll
    for (int mm = 0; mm < 3; ++mm)
#pragma unroll
      for (int rg = 0; rg < 4; ++rg) {
        const int R = (mt0 + mm) * 16 + erow + rg;
        const int C = nt0 * 16 + ecol;
        float v = 0.f;
        if (R < NN) {
          const int dg = offsL[R + 1] - offsL[R];
          const float inv = (dg > 0) ? 1.f / (float)dg : 1.f;
          const float sf  = (dg > 0) ? 1.f : 0.f;
          v = fmaxf(accU[mm][rg] + accT[mm][rg] * inv + sf * bias[1][C] + bias[2][C], 0.f);
        }
        *(unsigned short*)((char*)bufP + swzu(R, C * 2)) = f2b(v);
      }
  }
  __syncthreads();

  // ---- GEMM D: x = X + h2@Wu2 + bu2 (in place into X fp32) ----
  {
    f32x4 acc[3];
#pragma unroll
    for (int mm = 0; mm < 3; ++mm) acc[mm] = (f32x4)0.f;
    gemm3x1(bufP, wpk + 5 * 16384, lane, mt0, nt0, acc);
#pragma unroll
    for (int mm = 0; mm < 3; ++mm)
#pragma unroll
      for (int rg = 0; rg < 4; ++rg) {
        const int R = (mt0 + mm) * 16 + erow + rg;
        const int C = nt0 * 16 + ecol;
        if (R < NN) X[R][C] += acc[mm][rg] + bias[3][C];
      }
  }
  __syncthreads();

  // ---- LayerNorm per row + store ----
  for (int r = wave; r < NN; r += 16) {
    const float x0 = X[r][lane], x1 = X[r][lane + 64];
    float s = x0 + x1;
#pragma unroll
    for (int off = 32; off; off >>= 1) s += __shfl_xor(s, off);
    const float mu = s * (1.f / 128.f);
    const float d0 = x0 - mu, d1 = x1 - mu;
    float v = d0 * d0 + d1 * d1;
#pragma unroll
    for (int off = 32; off; off >>= 1) v += __shfl_xor(v, off);
    const float rstd = rsqrtf(v * (1.f / 128.f) + 1e-5f);
    const size_t o = ((size_t)b * NN + r) * HH;
    out[o + lane]      = d0 * rstd * bias[4][lane]      + bias[5][lane];
    out[o + lane + 64] = d1 * rstd * bias[4][lane + 64] + bias[5][lane + 64];
  }
}

// ================= fp32 fallback (known-good, used only if ws too small) =====
__device__ __forceinline__ void gemm_acc_f32(const float (*A)[HH], const float* __restrict__ Wg,
                                             int c, int row0, int nr, float (&acc)[41]) {
  float w[8];
#pragma unroll
  for (int j = 0; j < 8; ++j) w[j] = Wg[j * HH + c];
  for (int k0 = 0; k0 < HH; k0 += 8) {
    float wn[8];
    if (k0 + 8 < HH) {
#pragma unroll
      for (int j = 0; j < 8; ++j) wn[j] = Wg[(k0 + 8 + j) * HH + c];
    }
#pragma unroll
    for (int i = 0; i < 41; ++i) {
      if (i < nr) {
        const float4 a0 = *(const float4*)&A[row0 + i][k0];
        const float4 a1 = *(const float4*)&A[row0 + i][k0 + 4];
        acc[i] += a0.x * w[0] + a0.y * w[1] + a0.z * w[2] + a0.w * w[3]
                + a1.x * w[4] + a1.y * w[5] + a1.z * w[6] + a1.w * w[7];
      }
    }
#pragma unroll
    for (int j = 0; j < 8; ++j) w[j] = wn[j];
  }
}

__global__ __launch_bounds__(256, 1)
void mpnn_fused_kernel(const float* __restrict__ node, const int* __restrict__ eidx,
                       const float* __restrict__ Wm1, const float* __restrict__ bm1,
                       const float* __restrict__ Wm2, const float* __restrict__ bm2,
                       const float* __restrict__ Wu1, const float* __restrict__ bu1,
                       const float* __restrict__ Wu2, const float* __restrict__ bu2,
                       const float* __restrict__ gamma_, const float* __restrict__ beta_,
                       float* __restrict__ out) {
  __shared__ float X[NN][HH];
  __shared__ float Pb[NN][HH];
  __shared__ float Qb[NN][HH];
  __shared__ int   edg[2 * EE];
  __shared__ int   csr[EE];
  __shared__ int   offs[NN + 1];
  __shared__ int   cnt3[3][NN];
  __shared__ int   base3[3][NN];
  __shared__ float biases[6][HH];

  const int tid  = threadIdx.x;
  const int lane = tid & 63;
  const int wave = tid >> 6;
  const int b    = blockIdx.x;

  {
    const float4* nf4 = (const float4*)(node + (size_t)b * NN * HH);
    float4* X4 = (float4*)&X[0][0];
    for (int i = tid; i < NN * HH / 4; i += 256) X4[i] = nf4[i];
    for (int i = tid; i < 2 * EE; i += 256) edg[i] = eidx[i];
    if (tid < HH) {
      biases[0][tid] = bm1[tid]; biases[1][tid] = bm2[tid];
      biases[2][tid] = bu1[tid]; biases[3][tid] = bu2[tid];
      biases[4][tid] = gamma_[tid]; biases[5][tid] = beta_[tid];
    }
  }
  __syncthreads();
  if (tid < 3 * NN) {
    const int t = tid % NN, ch = tid / NN;
    const int e0 = ch * 540, e1 = e0 + 540;
    int cnt = 0;
    for (int e = e0; e < e1; ++e) cnt += (edg[EE + e] == t);
    cnt3[ch][t] = cnt;
  }
  __syncthreads();
  if (tid == 0) {
    int run = 0;
    for (int t = 0; t < NN; ++t) {
      offs[t] = run;
      base3[0][t] = run;
      base3[1][t] = base3[0][t] + cnt3[0][t];
      base3[2][t] = base3[1][t] + cnt3[1][t];
      run = base3[2][t] + cnt3[2][t];
    }
    offs[NN] = run;
  }
  __syncthreads();
  if (tid < 3 * NN) {
    const int t = tid % NN, ch = tid / NN;
    const int e0 = ch * 540, e1 = e0 + 540;
    int pos = base3[ch][t];
    for (int e = e0; e < e1; ++e)
      if (edg[EE + e] == t) csr[pos++] = edg[e];
  }
  __syncthreads();

  const int c    = ((wave & 1) << 6) | lane;
  const int row0 = (wave >> 1) ? 41 : 0;
  const int nr   = (wave >> 1) ? 40 : 41;

  {
    float acc[41];
#pragma unroll
    for (int i = 0; i < 41; ++i) acc[i] = 0.f;
    gemm_acc_f32(X, Wm1, c, row0, nr, acc);
#pragma unroll
    for (int i = 0; i < 41; ++i) if (i < nr) Pb[row0 + i][c] = acc[i];
  }
  {
    float acc[41];
#pragma unroll
    for (int i = 0; i < 41; ++i) acc[i] = 0.f;
    gemm_acc_f32(X, Wm1 + HH * HH, c, row0, nr, acc);
#pragma unroll
    for (int i = 0; i < 41; ++i) if (i < nr) Qb[row0 + i][c] = acc[i];
  }
  __syncthreads();

  for (int t = wave; t < NN; t += 4) {
    const int o0 = offs[t], o1 = offs[t + 1];
    const float q0 = Qb[t][lane]      + biases[0][lane];
    const float q1 = Qb[t][lane + 64] + biases[0][lane + 64];
    float h0 = 0.f, h1 = 0.f;
    for (int e = o0; e < o1; ++e) {
      const int s = csr[e];
      h0 += fmaxf(Pb[s][lane]      + q0, 0.f);
      h1 += fmaxf(Pb[s][lane + 64] + q1, 0.f);
    }
    Qb[t][lane]      = h0;
    Qb[t][lane + 64] = h1;
  }
  __syncthreads();

  {
    float acc[41];
#pragma unroll
    for (int i = 0; i < 41; ++i) acc[i] = 0.f;
    gemm_acc_f32(Qb, Wm2, c, row0, nr, acc);
#pragma unroll
    for (int i = 0; i < 41; ++i) if (i < nr) {
      const int r = row0 + i;
      const float d = (float)(offs[r + 1] - offs[r]);
      Pb[r][c] = (acc[i] + d * biases[1][c]) * (1.f / fmaxf(d, 1.f));
    }
  }
  __syncthreads();

  {
    float acc[41];
#pragma unroll
    for (int i = 0; i < 41; ++i) acc[i] = 0.f;
    gemm_acc_f32(X,  Wu1,           c, row0, nr, acc);
    gemm_acc_f32(Pb, Wu1 + HH * HH, c, row0, nr, acc);
#pragma unroll
    for (int i = 0; i < 41; ++i) if (i < nr)
      Qb[row0 + i][c] = fmaxf(acc[i] + biases[2][c], 0.f);
  }
  __syncthreads();

  {
    float acc[41];
#pragma unroll
    for (int i = 0; i < 41; ++i) acc[i] = 0.f;
    gemm_acc_f32(Qb, Wu2, c, row0, nr, acc);
#pragma unroll
    for (int i = 0; i < 41; ++i) if (i < nr) {
      const int r = row0 + i;
      X[r][c] = X[r][c] + acc[i] + biases[3][c];
    }
  }
  __syncthreads();

  for (int r = wave; r < NN; r += 4) {
    const float x0 = X[r][lane], x1 = X[r][lane + 64];
    float s = x0 + x1;
#pragma unroll
    for (int off = 32; off; off >>= 1) s += __shfl_xor(s, off);
    const float mu = s * (1.f / 128.f);
    const float d0 = x0 - mu, d1 = x1 - mu;
    float v = d0 * d0 + d1 * d1;
#pragma unroll
    for (int off = 32; off; off >>= 1) v += __shfl_xor(v, off);
    const float rstd = rsqrtf(v * (1.f / 128.f) + 1e-5f);
    const size_t o = ((size_t)b * NN + r) * HH;
    out[o + lane]      = d0 * rstd * biases[4][lane]      + biases[5][lane];
    out[o + lane + 64] = d1 * rstd * biases[4][lane + 64] + biases[5][lane + 64];
  }
}

extern "C" void kernel_launch(void* const* d_in, const int* in_sizes, int n_in,
                              void* d_out, int out_size, void* d_ws, size_t ws_size,
                              hipStream_t stream) {
  (void)in_sizes; (void)n_in; (void)out_size;
  const float* node  = (const float*)d_in[0];
  const int*   eidx  = (const int*)  d_in[1];
  const float* Wm1   = (const float*)d_in[2];
  const float* bm1   = (const float*)d_in[3];
  const float* Wm2   = (const float*)d_in[4];
  const float* bm2   = (const float*)d_in[5];
  const float* Wu1   = (const float*)d_in[6];
  const float* bu1   = (const float*)d_in[7];
  const float* Wu2   = (const float*)d_in[8];
  const float* bu2   = (const float*)d_in[9];
  const float* gamma_= (const float*)d_in[10];
  const float* beta_ = (const float*)d_in[11];
  float* outp = (float*)d_out;

  if (ws_size >= (size_t)WS_NEED) {
    char* ws = (char*)d_ws;
    hipLaunchKernelGGL(setup_kernel, dim3(13), dim3(1024), 0, stream,
                       Wm1, Wm2, Wu1, Wu2, bm2, eidx, ws);
    hipLaunchKernelGGL(mpnn_mfma3_kernel, dim3(256), dim3(1024), 0, stream,
                       node, bm1, bu1, bu2, gamma_, beta_, ws, outp);
  } else {
    hipLaunchKernelGGL(mpnn_fused_kernel, dim3(256), dim3(256), 0, stream,
                       node, eidx, Wm1, bm1, Wm2, bm2, Wu1, bu1, Wu2, bu2,
                       gamma_, beta_, outp);
  }
}

// Round 6
// 41.780 us; speedup vs baseline: 5.6387x; 1.0891x over previous
//
#include <hip/hip_runtime.h>
#include <hip/hip_bf16.h>

// Fused MPNN layer, B=256, N=81, H=128, E=1620 — MFMA bf16.
//   P = X @ Wm1[:H],  Q' = X @ Wm1[H:] + bm1
//   Hsum[t] = sum_{e: tgt=t} relu(P[src_e] + Q'[t])
//   Folded:  agg@Wu1b = (Hsum@Wc)*inv_deg + 1[deg>0]*bc,  Wc=Wm2@Wu1b, bc=bm2@Wu1b
//   h2 = relu(X@Wu1t + (Hsum@Wc)*inv + s*bc + bu1)
//   x  = X + h2 @ Wu2 + bu2 ;  out = LayerNorm(x)*gamma + beta
// Setup (grid 13 x 1024): blocks 0-7 pack {Wm1t,Wm1b,Wu1t,Wu2}; block 8 builds
//   deterministic CSR via per-chunk ballot match-masks (stable, ~1.5 us);
//   blocks 9-12 compute+pack Wc, block 9 also bc.
// Main (grid 256, 1024 thr = 16 waves): whole layer per batch in LDS.

#define NN 81
#define HH 128
#define EE 1620
#define NCHK 26                         // ceil(EE/64)
#define MPAD 96
#define WB_BYTES 196608                 // 6 * 16384 ushorts (slot4 unused)
#define OFFS_OFF (WB_BYTES)             // int offs[82]
#define CSR_OFF  (OFFS_OFF + 82 * 4)    // int csr[1620]
#define BC_OFF   (CSR_OFF + EE * 4)     // float bc[128]
#define WS_NEED  (BC_OFF + HH * 4)

typedef __attribute__((ext_vector_type(8))) short bf16x8;
typedef __attribute__((ext_vector_type(8))) unsigned short ushort8v;
typedef __attribute__((ext_vector_type(4))) float f32x4;

__device__ __forceinline__ unsigned short f2b(float f) {
  union { float f; unsigned u; } v; v.f = f;
  unsigned r = v.u + 0x7fffu + ((v.u >> 16) & 1u);
  return (unsigned short)(r >> 16);
}
__device__ __forceinline__ float b2f(unsigned short h) {
  union { unsigned u; float f; } v; v.u = ((unsigned)h) << 16;
  return v.f;
}
__device__ __forceinline__ unsigned f2b2(float x, float y) {  // packed RNE pair
  float2 f; f.x = x; f.y = y;
  union { __hip_bfloat162 h; unsigned u; } v;
  v.h = __float22bfloat162_rn(f);
  return v.u;
}
__device__ __forceinline__ unsigned swzu(int r, int laneb) {
  return ((unsigned)(r * 256 + laneb)) ^ ((unsigned)((r & 7) << 4));
}

// ---------------- setup kernel ------------------------------------------------
__global__ __launch_bounds__(1024)
void setup_kernel(const float* __restrict__ Wm1, const float* __restrict__ Wm2,
                  const float* __restrict__ Wu1, const float* __restrict__ Wu2,
                  const float* __restrict__ bm2, const int* __restrict__ eidx,
                  char* __restrict__ ws) {
  __shared__ __align__(16) char arena[81920];
  const int tid = threadIdx.x;

  if (blockIdx.x < 8) {
    // ---- pack 4 source mats: 8*1024 threads = 4 mats * 8 nt * 4 ks * 64 ----
    const int gid = blockIdx.x * 1024 + tid;
    const int lane = gid & 63;
    const int t = gid >> 6;                 // mat*32 + nt*4 + ks  (0..127)
    const int ks = t & 3, nt = (t >> 2) & 7, mat = t >> 5;
    const float* src;
    int slot;
    if (mat == 0)      { src = Wm1;           slot = 0; }
    else if (mat == 1) { src = Wm1 + HH * HH; slot = 1; }
    else if (mat == 2) { src = Wu1;           slot = 3; }
    else               { src = Wu2;           slot = 5; }
    const int c = nt * 16 + (lane & 15);
    const int k0 = ks * 32 + (lane >> 4) * 8;
    bf16x8 pv;
#pragma unroll
    for (int j = 0; j < 8; ++j) pv[j] = (short)f2b(src[(k0 + j) * HH + c]);
    *(bf16x8*)((unsigned short*)ws + (size_t)slot * 16384 + (((nt * 4 + ks) * 64) + lane) * 8) = pv;
    return;
  }

  if (blockIdx.x == 8) {
    // ---- deterministic CSR via ballot match-masks (stable counting sort) ----
    int* srcE  = (int*)arena;            // EE
    int* tgtE  = srcE + EE;              // EE (contiguous with srcE: eidx layout)
    int* rankS = tgtE + EE;              // EE
    int* cntC  = rankS + EE;             // NCHK*NN
    int* tot   = cntC + NCHK * NN;       // NN
    int* scanS = tot + NN;               // 128
    int* wsumS = scanS + 128;            // 2
    int* offsS = wsumS + 2;              // NN+1
    for (int i = tid; i < NCHK * NN; i += 1024) cntC[i] = 0;
    for (int i = tid; i < 2 * EE; i += 1024) srcE[i] = eidx[i];
    __syncthreads();
    const int lane = tid & 63, wv = tid >> 6;
    for (int c = wv; c < NCHK; c += 16) {
      const int e = c * 64 + lane;
      const bool ok = (e < EE);
      const int t = ok ? tgtE[e] : -1;
      unsigned long long mymask = 0;
#pragma unroll
      for (int i = 0; i < 64; ++i) {
        const int ti = __shfl(t, i);
        const unsigned long long bal = __ballot(t == ti);
        if (i == lane) mymask = bal;
      }
      if (ok) {
        const int rank = __popcll(mymask & ((1ull << lane) - 1ull));
        rankS[e] = rank;
        if (rank == 0) cntC[c * NN + t] = __popcll(mymask);
      }
    }
    __syncthreads();
    if (tid < NN) {
      int s = 0;
#pragma unroll
      for (int c = 0; c < NCHK; ++c) s += cntC[c * NN + tid];
      tot[tid] = s;
    }
    __syncthreads();
    if (tid < 128) {
      const int l = tid & 63, w = tid >> 6;
      int inc = (tid < NN) ? tot[tid] : 0;
#pragma unroll
      for (int d = 1; d < 64; d <<= 1) {
        int u = __shfl_up(inc, d);
        if (l >= d) inc += u;
      }
      scanS[tid] = inc;
      if (l == 63) wsumS[w] = inc;
    }
    __syncthreads();
    if (tid < 128) {
      const int w = tid >> 6;
      const int inc = scanS[tid] + (w ? wsumS[0] : 0);
      if (tid < NN) offsS[tid] = inc - tot[tid];
      if (tid == NN - 1) offsS[NN] = inc;
    }
    __syncthreads();
    if (tid < NN) {  // chunk bases: cntC[c][t] := offs[t] + sum_{c'<c} cnt
      int run = offsS[tid];
#pragma unroll
      for (int c = 0; c < NCHK; ++c) {
        const int tmp = cntC[c * NN + tid];
        cntC[c * NN + tid] = run;
        run += tmp;
      }
    }
    __syncthreads();
    int* wofs = (int*)(ws + OFFS_OFF);
    int* wcsr = (int*)(ws + CSR_OFF);
    for (int i = tid; i <= NN; i += 1024) wofs[i] = offsS[i];
    for (int e = tid; e < EE; e += 1024) {
      const int t = tgtE[e];
      wcsr[cntC[(e >> 6) * NN + t] + rankS[e]] = srcE[e];
    }
    return;
  }

  // ---- blocks 9-12: Wc = Wm2 @ Wu1b, rows [32*bs, 32*bs+32); pack slot 2 ----
  {
    const int bs = blockIdx.x - 9;      // = ks slice
    float* WuL = (float*)arena;         // [128][128]
    float* WmL = WuL + HH * HH;         // [32][128]
    const float* Wu1b = Wu1 + HH * HH;
    float4* WuL4 = (float4*)WuL;
    const float4* src4 = (const float4*)Wu1b;
    for (int i = tid; i < HH * HH / 4; i += 1024) WuL4[i] = src4[i];
    const float4* wm4 = (const float4*)(Wm2 + bs * 32 * HH);
    float4* WmL4 = (float4*)WmL;
    if (tid < 32 * HH / 4) WmL4[tid] = wm4[tid];
    __syncthreads();
    const int kk = tid >> 5;            // 0..31 local row
    const int k  = bs * 32 + kk;
    const int cg = tid & 31;            // float4 col group
    f32x4 acc = (f32x4)0.f;
    for (int j = 0; j < HH; ++j) {
      const float a = WmL[kk * HH + j];
      const float4 w = WuL4[j * 32 + cg];
      acc[0] += a * w.x; acc[1] += a * w.y; acc[2] += a * w.z; acc[3] += a * w.w;
    }
    unsigned short* dst = (unsigned short*)ws;
#pragma unroll
    for (int q = 0; q < 4; ++q) {
      const int c = cg * 4 + q;
      const int nt = c >> 4;
      const int l = (((k & 31) >> 3) << 4) | (c & 15);
      dst[(size_t)2 * 16384 + (((nt * 4 + bs) * 64) + l) * 8 + (k & 7)] = f2b(acc[q]);
    }
    if (bs == 0 && tid < HH) {
      float s = 0.f;
      for (int j = 0; j < HH; ++j) s += bm2[j] * WuL[j * HH + tid];
      ((float*)(ws + BC_OFF))[tid] = s;
    }
  }
}

// ---------------- MFMA tile GEMM helpers (per wave: 3 M-tiles x 1 N-tile) -----
__device__ __forceinline__ void gemm3x1(const unsigned short* Ab, const unsigned short* Wp,
                                        int lane, int mt0, int nt0, f32x4 acc[3]) {
  bf16x8 Bf[4];
#pragma unroll
  for (int ks = 0; ks < 4; ++ks)
    Bf[ks] = *(const bf16x8*)(Wp + ((nt0 * 4 + ks) * 64 + lane) * 8);
  const int rl = lane & 15;
  const int kb = (lane >> 4) * 16;
  const unsigned swz = (unsigned)((rl & 7) << 4);
#pragma unroll
  for (int ks = 0; ks < 4; ++ks)
#pragma unroll
    for (int mm = 0; mm < 3; ++mm) {
      const int r = (mt0 + mm) * 16 + rl;
      const unsigned byte = (unsigned)(r * 256) + (((unsigned)(ks * 64 + kb)) ^ swz);
      bf16x8 a = *(const bf16x8*)((const char*)Ab + byte);
      acc[mm] = __builtin_amdgcn_mfma_f32_16x16x32_bf16(a, Bf[ks], acc[mm], 0, 0, 0);
    }
}

// dual-B, same A
__device__ __forceinline__ void gemm3x1x2(const unsigned short* Ab,
                                          const unsigned short* Wp0, const unsigned short* Wp1,
                                          int lane, int mt0, int nt0,
                                          f32x4 acc0[3], f32x4 acc1[3]) {
  bf16x8 B0[4], B1[4];
#pragma unroll
  for (int ks = 0; ks < 4; ++ks) {
    B0[ks] = *(const bf16x8*)(Wp0 + ((nt0 * 4 + ks) * 64 + lane) * 8);
    B1[ks] = *(const bf16x8*)(Wp1 + ((nt0 * 4 + ks) * 64 + lane) * 8);
  }
  const int rl = lane & 15;
  const int kb = (lane >> 4) * 16;
  const unsigned swz = (unsigned)((rl & 7) << 4);
#pragma unroll
  for (int ks = 0; ks < 4; ++ks)
#pragma unroll
    for (int mm = 0; mm < 3; ++mm) {
      const int r = (mt0 + mm) * 16 + rl;
      const unsigned byte = (unsigned)(r * 256) + (((unsigned)(ks * 64 + kb)) ^ swz);
      bf16x8 a = *(const bf16x8*)((const char*)Ab + byte);
      acc0[mm] = __builtin_amdgcn_mfma_f32_16x16x32_bf16(a, B0[ks], acc0[mm], 0, 0, 0);
      acc1[mm] = __builtin_amdgcn_mfma_f32_16x16x32_bf16(a, B1[ks], acc1[mm], 0, 0, 0);
    }
}

// dual-A, two B mats (T = Hsum@Wc, U = Xb@Wu1t share the K-loop)
__device__ __forceinline__ void gemm3x1_2A(const unsigned short* A0, const unsigned short* A1,
                                           const unsigned short* Wp0, const unsigned short* Wp1,
                                           int lane, int mt0, int nt0,
                                           f32x4 acc0[3], f32x4 acc1[3]) {
  bf16x8 B0[4], B1[4];
#pragma unroll
  for (int ks = 0; ks < 4; ++ks) {
    B0[ks] = *(const bf16x8*)(Wp0 + ((nt0 * 4 + ks) * 64 + lane) * 8);
    B1[ks] = *(const bf16x8*)(Wp1 + ((nt0 * 4 + ks) * 64 + lane) * 8);
  }
  const int rl = lane & 15;
  const int kb = (lane >> 4) * 16;
  const unsigned swz = (unsigned)((rl & 7) << 4);
#pragma unroll
  for (int ks = 0; ks < 4; ++ks)
#pragma unroll
    for (int mm = 0; mm < 3; ++mm) {
      const int r = (mt0 + mm) * 16 + rl;
      const unsigned byte = (unsigned)(r * 256) + (((unsigned)(ks * 64 + kb)) ^ swz);
      bf16x8 a0 = *(const bf16x8*)((const char*)A0 + byte);
      acc0[mm] = __builtin_amdgcn_mfma_f32_16x16x32_bf16(a0, B0[ks], acc0[mm], 0, 0, 0);
      bf16x8 a1 = *(const bf16x8*)((const char*)A1 + byte);
      acc1[mm] = __builtin_amdgcn_mfma_f32_16x16x32_bf16(a1, B1[ks], acc1[mm], 0, 0, 0);
    }
}

__global__ __launch_bounds__(1024, 4)
void mpnn_mfma4_kernel(const float* __restrict__ node,
                       const float* __restrict__ bm1,
                       const float* __restrict__ bu1, const float* __restrict__ bu2,
                       const float* __restrict__ gamma_, const float* __restrict__ beta_,
                       const char* __restrict__ ws,
                       float* __restrict__ out) {
  __shared__ float X[NN][HH];                 // fp32 for residual + LN
  __shared__ unsigned short Xb[MPAD * HH];    // swizzled bf16
  __shared__ unsigned short bufP[MPAD * HH];  // P -> h2
  __shared__ unsigned short bufQ[MPAD * HH];  // Q' -> Hsum
  __shared__ int   csrL[EE];
  __shared__ int   offsL[NN + 1];
  __shared__ float bias[6][HH];               // bm1,bc,bu1,bu2,gamma,beta

  const int tid  = threadIdx.x;
  const int lane = tid & 63;
  const int wave = tid >> 6;     // 0..15
  const int b    = blockIdx.x;

  const unsigned short* wpk = (const unsigned short*)ws;
  const int* wofs = (const int*)(ws + OFFS_OFF);
  const int* wcsr = (const int*)(ws + CSR_OFF);
  const float* wbc = (const float*)(ws + BC_OFF);

  // ---- stage: 3 prefetched loads/thread, packed bf16 conversion ----
  {
    const float4* nf4 = (const float4*)(node + (size_t)b * NN * HH);
    const int i2 = tid + 2048;
    const bool has2 = (i2 < NN * HH / 4);     // NN*HH/4 = 2592
    float4 v0 = nf4[tid];
    float4 v1 = nf4[tid + 1024];
    float4 v2 = has2 ? nf4[i2] : make_float4(0.f, 0.f, 0.f, 0.f);
#pragma unroll
    for (int k = 0; k < 3; ++k) {
      const int i = tid + k * 1024;
      if (k == 2 && !has2) break;
      const float4 v = (k == 0) ? v0 : (k == 1) ? v1 : v2;
      const int r = i >> 5, c = (i & 31) * 4;
      *(float4*)&X[r][c] = v;
      unsigned pk0 = f2b2(v.x, v.y), pk1 = f2b2(v.z, v.w);
      uint2 pv; pv.x = pk0; pv.y = pk1;
      *(uint2*)((char*)Xb + swzu(r, c * 2)) = pv;
    }
    if (tid < (MPAD - NN) * 16) {   // zero pad rows 81..95
      const int r = NN + tid / 16, m = tid % 16;
      ushort8v z = {0,0,0,0,0,0,0,0};
      *(ushort8v*)((char*)Xb + swzu(r, m * 16)) = z;
    }
    for (int i = tid; i < EE; i += 1024) csrL[i] = wcsr[i];
    if (tid < NN + 1) offsL[tid] = wofs[tid];
    if (tid < HH) {
      bias[0][tid] = bm1[tid];  bias[1][tid] = wbc[tid];
      bias[2][tid] = bu1[tid];  bias[3][tid] = bu2[tid];
      bias[4][tid] = gamma_[tid]; bias[5][tid] = beta_[tid];
    }
  }
  __syncthreads();

  // ---- wave tile map: 16 waves = 8 N-tiles x 2 M-halves (3 M-tiles each) ----
  const int nt0 = wave & 7;
  const int mt0 = 3 * (wave >> 3);
  const int erow = (lane >> 4) * 4;
  const int ecol = lane & 15;

  // ---- GEMM A: P = Xb@Wm1t -> bufP ; Q' = Xb@Wm1b + bm1 -> bufQ ----
  {
    f32x4 accP[3], accQ[3];
#pragma unroll
    for (int mm = 0; mm < 3; ++mm) { accP[mm] = (f32x4)0.f; accQ[mm] = (f32x4)0.f; }
    gemm3x1x2(Xb, wpk, wpk + 16384, lane, mt0, nt0, accP, accQ);
#pragma unroll
    for (int mm = 0; mm < 3; ++mm)
#pragma unroll
      for (int rg = 0; rg < 4; ++rg) {
        const int R = (mt0 + mm) * 16 + erow + rg;
        const int C = nt0 * 16 + ecol;
        const unsigned byte = swzu(R, C * 2);
        const bool ok = (R < NN);
        *(unsigned short*)((char*)bufP + byte) = ok ? f2b(accP[mm][rg]) : (unsigned short)0;
        *(unsigned short*)((char*)bufQ + byte) = ok ? f2b(accQ[mm][rg] + bias[0][C]) : (unsigned short)0;
      }
  }
  __syncthreads();

  // ---- edge aggregation (x4 unrolled): Hsum[t] = sum relu(P[s]+Q'[t]) -> bufQ
  {
    const int lb = lane * 4;
    for (int t = wave; t < NN; t += 16) {
      const unsigned qbyte = swzu(t, lb);
      const unsigned pq = *(const unsigned*)((const char*)bufQ + qbyte);
      const float q0 = b2f((unsigned short)(pq & 0xffff));
      const float q1 = b2f((unsigned short)(pq >> 16));
      float h0 = 0.f, h1 = 0.f, g0 = 0.f, g1 = 0.f;
      int e = offsL[t];
      const int o1 = offsL[t + 1];
      for (; e + 4 <= o1; e += 4) {
        const int s0 = csrL[e], s1 = csrL[e + 1], s2 = csrL[e + 2], s3 = csrL[e + 3];
        const unsigned p0 = *(const unsigned*)((const char*)bufP + swzu(s0, lb));
        const unsigned p1 = *(const unsigned*)((const char*)bufP + swzu(s1, lb));
        const unsigned p2 = *(const unsigned*)((const char*)bufP + swzu(s2, lb));
        const unsigned p3 = *(const unsigned*)((const char*)bufP + swzu(s3, lb));
        h0 += fmaxf(b2f((unsigned short)(p0 & 0xffff)) + q0, 0.f);
        h1 += fmaxf(b2f((unsigned short)(p0 >> 16))    + q1, 0.f);
        g0 += fmaxf(b2f((unsigned short)(p1 & 0xffff)) + q0, 0.f);
        g1 += fmaxf(b2f((unsigned short)(p1 >> 16))    + q1, 0.f);
        h0 += fmaxf(b2f((unsigned short)(p2 & 0xffff)) + q0, 0.f);
        h1 += fmaxf(b2f((unsigned short)(p2 >> 16))    + q1, 0.f);
        g0 += fmaxf(b2f((unsigned short)(p3 & 0xffff)) + q0, 0.f);
        g1 += fmaxf(b2f((unsigned short)(p3 >> 16))    + q1, 0.f);
      }
      for (; e < o1; ++e) {
        const int s = csrL[e];
        const unsigned pp = *(const unsigned*)((const char*)bufP + swzu(s, lb));
        h0 += fmaxf(b2f((unsigned short)(pp & 0xffff)) + q0, 0.f);
        h1 += fmaxf(b2f((unsigned short)(pp >> 16))    + q1, 0.f);
      }
      h0 += g0; h1 += g1;
      const unsigned hv = (unsigned)f2b(h0) | ((unsigned)f2b(h1) << 16);
      *(unsigned*)((char*)bufQ + qbyte) = hv;
    }
  }
  __syncthreads();

  // ---- GEMM BC: T = Hsum@Wc ; U = Xb@Wu1t ;
  //      h2 = relu(U + T*inv_deg + s*bc + bu1) -> bufP ----
  {
    f32x4 accT[3], accU[3];
#pragma unroll
    for (int mm = 0; mm < 3; ++mm) { accT[mm] = (f32x4)0.f; accU[mm] = (f32x4)0.f; }
    gemm3x1_2A(bufQ, Xb, wpk + 2 * 16384, wpk + 3 * 16384, lane, mt0, nt0, accT, accU);
#pragma unroll
    for (int mm = 0; mm < 3; ++mm)
#pragma unroll
      for (int rg = 0; rg < 4; ++rg) {
        const int R = (mt0 + mm) * 16 + erow + rg;
        const int C = nt0 * 16 + ecol;
        float v = 0.f;
        if (R < NN) {
          const int dg = offsL[R + 1] - offsL[R];
          const float inv = (dg > 0) ? 1.f / (float)dg : 1.f;
          const float sf  = (dg > 0) ? 1.f : 0.f;
          v = fmaxf(accU[mm][rg] + accT[mm][rg] * inv + sf * bias[1][C] + bias[2][C], 0.f);
        }
        *(unsigned short*)((char*)bufP + swzu(R, C * 2)) = f2b(v);
      }
  }
  __syncthreads();

  // ---- GEMM D: x = X + h2@Wu2 + bu2 (in place into X fp32) ----
  {
    f32x4 acc[3];
#pragma unroll
    for (int mm = 0; mm < 3; ++mm) acc[mm] = (f32x4)0.f;
    gemm3x1(bufP, wpk + 5 * 16384, lane, mt0, nt0, acc);
#pragma unroll
    for (int mm = 0; mm < 3; ++mm)
#pragma unroll
      for (int rg = 0; rg < 4; ++rg) {
        const int R = (mt0 + mm) * 16 + erow + rg;
        const int C = nt0 * 16 + ecol;
        if (R < NN) X[R][C] += acc[mm][rg] + bias[3][C];
      }
  }
  __syncthreads();

  // ---- LayerNorm per row + store ----
  for (int r = wave; r < NN; r += 16) {
    const float x0 = X[r][lane], x1 = X[r][lane + 64];
    float s = x0 + x1;
#pragma unroll
    for (int off = 32; off; off >>= 1) s += __shfl_xor(s, off);
    const float mu = s * (1.f / 128.f);
    const float d0 = x0 - mu, d1 = x1 - mu;
    float v = d0 * d0 + d1 * d1;
#pragma unroll
    for (int off = 32; off; off >>= 1) v += __shfl_xor(v, off);
    const float rstd = rsqrtf(v * (1.f / 128.f) + 1e-5f);
    const size_t o = ((size_t)b * NN + r) * HH;
    out[o + lane]      = d0 * rstd * bias[4][lane]      + bias[5][lane];
    out[o + lane + 64] = d1 * rstd * bias[4][lane + 64] + bias[5][lane + 64];
  }
}

// ================= fp32 fallback (known-good, used only if ws too small) =====
__device__ __forceinline__ void gemm_acc_f32(const float (*A)[HH], const float* __restrict__ Wg,
                                             int c, int row0, int nr, float (&acc)[41]) {
  float w[8];
#pragma unroll
  for (int j = 0; j < 8; ++j) w[j] = Wg[j * HH + c];
  for (int k0 = 0; k0 < HH; k0 += 8) {
    float wn[8];
    if (k0 + 8 < HH) {
#pragma unroll
      for (int j = 0; j < 8; ++j) wn[j] = Wg[(k0 + 8 + j) * HH + c];
    }
#pragma unroll
    for (int i = 0; i < 41; ++i) {
      if (i < nr) {
        const float4 a0 = *(const float4*)&A[row0 + i][k0];
        const float4 a1 = *(const float4*)&A[row0 + i][k0 + 4];
        acc[i] += a0.x * w[0] + a0.y * w[1] + a0.z * w[2] + a0.w * w[3]
                + a1.x * w[4] + a1.y * w[5] + a1.z * w[6] + a1.w * w[7];
      }
    }
#pragma unroll
    for (int j = 0; j < 8; ++j) w[j] = wn[j];
  }
}

__global__ __launch_bounds__(256, 1)
void mpnn_fused_kernel(const float* __restrict__ node, const int* __restrict__ eidx,
                       const float* __restrict__ Wm1, const float* __restrict__ bm1,
                       const float* __restrict__ Wm2, const float* __restrict__ bm2,
                       const float* __restrict__ Wu1, const float* __restrict__ bu1,
                       const float* __restrict__ Wu2, const float* __restrict__ bu2,
                       const float* __restrict__ gamma_, const float* __restrict__ beta_,
                       float* __restrict__ out) {
  __shared__ float X[NN][HH];
  __shared__ float Pb[NN][HH];
  __shared__ float Qb[NN][HH];
  __shared__ int   edg[2 * EE];
  __shared__ int   csr[EE];
  __shared__ int   offs[NN + 1];
  __shared__ int   cnt3[3][NN];
  __shared__ int   base3[3][NN];
  __shared__ float biases[6][HH];

  const int tid  = threadIdx.x;
  const int lane = tid & 63;
  const int wave = tid >> 6;
  const int b    = blockIdx.x;

  {
    const float4* nf4 = (const float4*)(node + (size_t)b * NN * HH);
    float4* X4 = (float4*)&X[0][0];
    for (int i = tid; i < NN * HH / 4; i += 256) X4[i] = nf4[i];
    for (int i = tid; i < 2 * EE; i += 256) edg[i] = eidx[i];
    if (tid < HH) {
      biases[0][tid] = bm1[tid]; biases[1][tid] = bm2[tid];
      biases[2][tid] = bu1[tid]; biases[3][tid] = bu2[tid];
      biases[4][tid] = gamma_[tid]; biases[5][tid] = beta_[tid];
    }
  }
  __syncthreads();
  if (tid < 3 * NN) {
    const int t = tid % NN, ch = tid / NN;
    const int e0 = ch * 540, e1 = e0 + 540;
    int cnt = 0;
    for (int e = e0; e < e1; ++e) cnt += (edg[EE + e] == t);
    cnt3[ch][t] = cnt;
  }
  __syncthreads();
  if (tid == 0) {
    int run = 0;
    for (int t = 0; t < NN; ++t) {
      offs[t] = run;
      base3[0][t] = run;
      base3[1][t] = base3[0][t] + cnt3[0][t];
      base3[2][t] = base3[1][t] + cnt3[1][t];
      run = base3[2][t] + cnt3[2][t];
    }
    offs[NN] = run;
  }
  __syncthreads();
  if (tid < 3 * NN) {
    const int t = tid % NN, ch = tid / NN;
    const int e0 = ch * 540, e1 = e0 + 540;
    int pos = base3[ch][t];
    for (int e = e0; e < e1; ++e)
      if (edg[EE + e] == t) csr[pos++] = edg[e];
  }
  __syncthreads();

  const int c    = ((wave & 1) << 6) | lane;
  const int row0 = (wave >> 1) ? 41 : 0;
  const int nr   = (wave >> 1) ? 40 : 41;

  {
    float acc[41];
#pragma unroll
    for (int i = 0; i < 41; ++i) acc[i] = 0.f;
    gemm_acc_f32(X, Wm1, c, row0, nr, acc);
#pragma unroll
    for (int i = 0; i < 41; ++i) if (i < nr) Pb[row0 + i][c] = acc[i];
  }
  {
    float acc[41];
#pragma unroll
    for (int i = 0; i < 41; ++i) acc[i] = 0.f;
    gemm_acc_f32(X, Wm1 + HH * HH, c, row0, nr, acc);
#pragma unroll
    for (int i = 0; i < 41; ++i) if (i < nr) Qb[row0 + i][c] = acc[i];
  }
  __syncthreads();

  for (int t = wave; t < NN; t += 4) {
    const int o0 = offs[t], o1 = offs[t + 1];
    const float q0 = Qb[t][lane]      + biases[0][lane];
    const float q1 = Qb[t][lane + 64] + biases[0][lane + 64];
    float h0 = 0.f, h1 = 0.f;
    for (int e = o0; e < o1; ++e) {
      const int s = csr[e];
      h0 += fmaxf(Pb[s][lane]      + q0, 0.f);
      h1 += fmaxf(Pb[s][lane + 64] + q1, 0.f);
    }
    Qb[t][lane]      = h0;
    Qb[t][lane + 64] = h1;
  }
  __syncthreads();

  {
    float acc[41];
#pragma unroll
    for (int i = 0; i < 41; ++i) acc[i] = 0.f;
    gemm_acc_f32(Qb, Wm2, c, row0, nr, acc);
#pragma unroll
    for (int i = 0; i < 41; ++i) if (i < nr) {
      const int r = row0 + i;
      const float d = (float)(offs[r + 1] - offs[r]);
      Pb[r][c] = (acc[i] + d * biases[1][c]) * (1.f / fmaxf(d, 1.f));
    }
  }
  __syncthreads();

  {
    float acc[41];
#pragma unroll
    for (int i = 0; i < 41; ++i) acc[i] = 0.f;
    gemm_acc_f32(X,  Wu1,           c, row0, nr, acc);
    gemm_acc_f32(Pb, Wu1 + HH * HH, c, row0, nr, acc);
#pragma unroll
    for (int i = 0; i < 41; ++i) if (i < nr)
      Qb[row0 + i][c] = fmaxf(acc[i] + biases[2][c], 0.f);
  }
  __syncthreads();

  {
    float acc[41];
#pragma unroll
    for (int i = 0; i < 41; ++i) acc[i] = 0.f;
    gemm_acc_f32(Qb, Wu2, c, row0, nr, acc);
#pragma unroll
    for (int i = 0; i < 41; ++i) if (i < nr) {
      const int r = row0 + i;
      X[r][c] = X[r][c] + acc[i] + biases[3][c];
    }
  }
  __syncthreads();

  for (int r = wave; r < NN; r += 4) {
    const float x0 = X[r][lane], x1 = X[r][lane + 64];
    float s = x0 + x1;
#pragma unroll
    for (int off = 32; off; off >>= 1) s += __shfl_xor(s, off);
    const float mu = s * (1.f / 128.f);
    const float d0 = x0 - mu, d1 = x1 - mu;
    float v = d0 * d0 + d1 * d1;
#pragma unroll
    for (int off = 32; off; off >>= 1) v += __shfl_xor(v, off);
    const float rstd = rsqrtf(v * (1.f / 128.f) + 1e-5f);
    const size_t o = ((size_t)b * NN + r) * HH;
    out[o + lane]      = d0 * rstd * biases[4][lane]      + biases[5][lane];
    out[o + lane + 64] = d1 * rstd * biases[4][lane + 64] + biases[5][lane + 64];
  }
}

extern "C" void kernel_launch(void* const* d_in, const int* in_sizes, int n_in,
                              void* d_out, int out_size, void* d_ws, size_t ws_size,
                              hipStream_t stream) {
  (void)in_sizes; (void)n_in; (void)out_size;
  const float* node  = (const float*)d_in[0];
  const int*   eidx  = (const int*)  d_in[1];
  const float* Wm1   = (const float*)d_in[2];
  const float* bm1   = (const float*)d_in[3];
  const float* Wm2   = (const float*)d_in[4];
  const float* bm2   = (const float*)d_in[5];
  const float* Wu1   = (const float*)d_in[6];
  const float* bu1   = (const float*)d_in[7];
  const float* Wu2   = (const float*)d_in[8];
  const float* bu2   = (const float*)d_in[9];
  const float* gamma_= (const float*)d_in[10];
  const float* beta_ = (const float*)d_in[11];
  float* outp = (float*)d_out;

  if (ws_size >= (size_t)WS_NEED) {
    char* ws = (char*)d_ws;
    hipLaunchKernelGGL(setup_kernel, dim3(13), dim3(1024), 0, stream,
                       Wm1, Wm2, Wu1, Wu2, bm2, eidx, ws);
    hipLaunchKernelGGL(mpnn_mfma4_kernel, dim3(256), dim3(1024), 0, stream,
                       node, bm1, bu1, bu2, gamma_, beta_, ws, outp);
  } else {
    hipLaunchKernelGGL(mpnn_fused_kernel, dim3(256), dim3(256), 0, stream,
                       node, eidx, Wm1, bm1, Wm2, bm2, Wu1, bu1, Wu2, bu2,
                       gamma_, beta_, outp);
  }
}